// Round 1
// baseline (3416.488 us; speedup 1.0000x reference)
//
#include <hip/hip_runtime.h>

#define NN 50000
#define EE 800000

// ---------------- degree / coefficient precompute ----------------

__global__ void deg_kernel(const int* __restrict__ dst, const float* __restrict__ w,
                           float* __restrict__ deg_w, float* __restrict__ deg_1, int E) {
    int e = blockIdx.x * 256 + threadIdx.x;
    if (e < E) {
        int d = dst[e];
        atomicAdd(&deg_w[d], w[e]);
        atomicAdd(&deg_1[d], 1.0f);
    }
}

__global__ void dinv_kernel(float* deg_w, float* deg_1, int N) {
    int i = blockIdx.x * 256 + threadIdx.x;
    if (i < N) {
        deg_w[i] = rsqrtf(deg_w[i] + 1.0f);   // in-place: deg -> D^-1/2
        deg_1[i] = rsqrtf(deg_1[i] + 1.0f);
    }
}

__global__ void coef_kernel(const int* __restrict__ src, const int* __restrict__ dst,
                            const float* __restrict__ w,
                            const float* __restrict__ dinv_w, const float* __restrict__ dinv_1,
                            float* __restrict__ coef_w, float* __restrict__ coef_1, int E) {
    int e = blockIdx.x * 256 + threadIdx.x;
    if (e < E) {
        int s = src[e], d = dst[e];
        coef_w[e] = dinv_w[s] * w[e] * dinv_w[d];
        coef_1[e] = dinv_1[s] * dinv_1[d];
    }
}

// ---------------- GEMM: H = act(X) @ W ----------------
// X [N,K] row-major, W [K,DOUT] row-major. Each thread: 4 rows x 4 cols.
template<int K, int DOUT, bool RELU_IN>
__global__ void gemm_kernel(const float* __restrict__ X, const float* __restrict__ W,
                            float* __restrict__ H, int N) {
    constexpr int CG = DOUT / 4;             // colgroups of 4
    constexpr int RPB = (256 / CG) * 4;      // rows per block
    int tx = threadIdx.x % CG;
    int ty = threadIdx.x / CG;
    int row0 = blockIdx.x * RPB + ty * 4;
    int col0 = tx * 4;

    float acc[4][4] = {};
    for (int k = 0; k < K; k += 4) {
        float4 w0 = *reinterpret_cast<const float4*>(&W[(k + 0) * DOUT + col0]);
        float4 w1 = *reinterpret_cast<const float4*>(&W[(k + 1) * DOUT + col0]);
        float4 w2 = *reinterpret_cast<const float4*>(&W[(k + 2) * DOUT + col0]);
        float4 w3 = *reinterpret_cast<const float4*>(&W[(k + 3) * DOUT + col0]);
#pragma unroll
        for (int r = 0; r < 4; ++r) {
            int row = row0 + r;
            if (row < N) {
                float4 x4 = *reinterpret_cast<const float4*>(&X[row * K + k]);
                if (RELU_IN) {
                    x4.x = fmaxf(x4.x, 0.0f); x4.y = fmaxf(x4.y, 0.0f);
                    x4.z = fmaxf(x4.z, 0.0f); x4.w = fmaxf(x4.w, 0.0f);
                }
                acc[r][0] += x4.x * w0.x + x4.y * w1.x + x4.z * w2.x + x4.w * w3.x;
                acc[r][1] += x4.x * w0.y + x4.y * w1.y + x4.z * w2.y + x4.w * w3.y;
                acc[r][2] += x4.x * w0.z + x4.y * w1.z + x4.z * w2.z + x4.w * w3.z;
                acc[r][3] += x4.x * w0.w + x4.y * w1.w + x4.z * w2.w + x4.w * w3.w;
            }
        }
    }
#pragma unroll
    for (int r = 0; r < 4; ++r) {
        int row = row0 + r;
        if (row < N) {
            float4 o = make_float4(acc[r][0], acc[r][1], acc[r][2], acc[r][3]);
            *reinterpret_cast<float4*>(&H[row * DOUT + col0]) = o;
        }
    }
}

// ---------------- out = H * dinv^2 + b (self-loop + bias) ----------------
template<int LOGD>
__global__ void init_out_kernel(const float* __restrict__ H, const float* __restrict__ dinv,
                                const float* __restrict__ b, float* __restrict__ out, int N) {
    constexpr int D = 1 << LOGD;
    int i = blockIdx.x * 256 + threadIdx.x;
    if (i < N * D) {
        int row = i >> LOGD;
        float di = dinv[row];
        out[i] = H[i] * di * di + b[i & (D - 1)];
    }
}

// ---------------- edge scatter: out[dst] += H[src] * coef ----------------
template<int D>   // one thread per (edge, feature), D in {32, 64}
__global__ void scatter_kernel(const int* __restrict__ src, const int* __restrict__ dst,
                               const float* __restrict__ coef, const float* __restrict__ H,
                               float* __restrict__ out, int E) {
    int t = blockIdx.x * 256 + threadIdx.x;
    int e = t / D;
    int f = t % D;
    if (e < E) {
        int s = src[e], d = dst[e];
        float c = coef[e];
        atomicAdd(&out[d * D + f], H[s * D + f] * c);
    }
}

__global__ void scatter256_kernel(const int* __restrict__ src, const int* __restrict__ dst,
                                  const float* __restrict__ coef, const float* __restrict__ H,
                                  float* __restrict__ out, int E) {
    int t = blockIdx.x * 256 + threadIdx.x;
    int e = t >> 6;          // 64 threads per edge
    int lane = t & 63;       // each thread does 4 consecutive features
    if (e < EE) {
        int s = src[e], d = dst[e];
        float c = coef[e];
        float4 h4 = *reinterpret_cast<const float4*>(&H[s * 256 + lane * 4]);
        float* o = &out[d * 256 + lane * 4];
        atomicAdd(o + 0, h4.x * c);
        atomicAdd(o + 1, h4.y * c);
        atomicAdd(o + 2, h4.z * c);
        atomicAdd(o + 3, h4.w * c);
    }
    (void)E;
}

__global__ void relu_kernel(float* __restrict__ p, int n) {
    int i = blockIdx.x * 256 + threadIdx.x;
    if (i < n) p[i] = fmaxf(p[i], 0.0f);
}

// ---------------- launch ----------------

extern "C" void kernel_launch(void* const* d_in, const int* in_sizes, int n_in,
                              void* d_out, int out_size, void* d_ws, size_t ws_size,
                              hipStream_t stream) {
    const float* x  = (const float*)d_in[0];
    const int*   ei = (const int*)d_in[1];
    const float* w  = (const float*)d_in[2];
    const float* W1 = (const float*)d_in[3];
    const float* b1 = (const float*)d_in[4];
    const float* W2 = (const float*)d_in[5];
    const float* b2 = (const float*)d_in[6];
    const float* W3 = (const float*)d_in[7];
    const float* b3 = (const float*)d_in[8];
    const float* W4 = (const float*)d_in[9];
    const float* b4 = (const float*)d_in[10];

    const int* src = ei;            // edge_index[0]
    const int* dst = ei + EE;       // edge_index[1]

    const int N = NN, E = EE;

    // workspace layout (floats)
    float* ws     = (float*)d_ws;
    float* dinv_w = ws;                       // N (50176 padded)
    float* dinv_1 = ws + 50176;               // N
    float* coef_w = ws + 100352;              // E
    float* coef_1 = ws + 900352;              // E
    float* bufA   = ws + 1700352;             // N*64
    float* bufB   = ws + 4900352;             // N*64
    float* bufBig = ws + 8100352;             // N*256  (end: 20,900,352 floats = 83.6 MB)

    float* recon = (float*)d_out;             // N*256
    float* zout  = (float*)d_out + NN * 256;  // N*32

    // ---- precompute normalization ----
    hipMemsetAsync(dinv_w, 0, N * sizeof(float), stream);
    hipMemsetAsync(dinv_1, 0, N * sizeof(float), stream);
    deg_kernel<<<(E + 255) / 256, 256, 0, stream>>>(dst, w, dinv_w, dinv_1, E);
    dinv_kernel<<<(N + 255) / 256, 256, 0, stream>>>(dinv_w, dinv_1, N);
    coef_kernel<<<(E + 255) / 256, 256, 0, stream>>>(src, dst, w, dinv_w, dinv_1,
                                                     coef_w, coef_1, E);

    // ---- layer 1: h1 = relu(conv(x, W1, b1, w))  [relu deferred into L2 gemm] ----
    gemm_kernel<256, 64, false><<<(N + 63) / 64, 256, 0, stream>>>(x, W1, bufA, N);
    init_out_kernel<6><<<(N * 64 + 255) / 256, 256, 0, stream>>>(bufA, dinv_w, b1, bufB, N);
    scatter_kernel<64><<<(E * 64 + 255) / 256, 256, 0, stream>>>(src, dst, coef_w, bufA, bufB, E);

    // ---- layer 2: z = relu(conv(h1, W2, b2, w)) -> d_out z region ----
    gemm_kernel<64, 32, true><<<(N + 127) / 128, 256, 0, stream>>>(bufB, W2, bufBig, N);
    init_out_kernel<5><<<(N * 32 + 255) / 256, 256, 0, stream>>>(bufBig, dinv_w, b2, zout, N);
    scatter_kernel<32><<<(E * 32 + 255) / 256, 256, 0, stream>>>(src, dst, coef_w, bufBig, zout, E);
    relu_kernel<<<(N * 32 + 255) / 256, 256, 0, stream>>>(zout, N * 32);

    // ---- layer 3: d = relu(conv(z, W3, b3, w))  [relu deferred into L4 gemm] ----
    gemm_kernel<32, 64, false><<<(N + 63) / 64, 256, 0, stream>>>(zout, W3, bufA, N);
    init_out_kernel<6><<<(N * 64 + 255) / 256, 256, 0, stream>>>(bufA, dinv_w, b3, bufB, N);
    scatter_kernel<64><<<(E * 64 + 255) / 256, 256, 0, stream>>>(src, dst, coef_w, bufA, bufB, E);

    // ---- layer 4: recon = conv(d, W4, b4, ones) -> d_out recon region ----
    gemm_kernel<64, 256, true><<<(N + 15) / 16, 256, 0, stream>>>(bufB, W4, bufBig, N);
    init_out_kernel<8><<<(N * 256 + 255) / 256, 256, 0, stream>>>(bufBig, dinv_1, b4, recon, N);
    scatter256_kernel<<<(E * 64 + 255) / 256, 256, 0, stream>>>(src, dst, coef_1, bufBig, recon, E);

    (void)in_sizes; (void)n_in; (void)out_size; (void)ws_size;
}

// Round 3
// 2326.283 us; speedup vs baseline: 1.4686x; 1.4686x over previous
//
#include <hip/hip_runtime.h>

#define NN 50000
#define EE 800000

// ---------------- degree / coefficient precompute (R1-proven) ----------------

__global__ void deg_kernel(const int* __restrict__ dst, const float* __restrict__ w,
                           float* __restrict__ deg_w, float* __restrict__ deg_1, int E) {
    int e = blockIdx.x * 256 + threadIdx.x;
    if (e < E) {
        int d = dst[e];
        atomicAdd(&deg_w[d], w[e]);
        atomicAdd(&deg_1[d], 1.0f);
    }
}

__global__ void dinv_kernel(float* deg_w, float* deg_1, int N) {
    int i = blockIdx.x * 256 + threadIdx.x;
    if (i < N) {
        deg_w[i] = rsqrtf(deg_w[i] + 1.0f);   // in-place: deg -> D^-1/2
        deg_1[i] = rsqrtf(deg_1[i] + 1.0f);
    }
}

__global__ void coef_kernel(const int* __restrict__ src, const int* __restrict__ dst,
                            const float* __restrict__ w,
                            const float* __restrict__ dinv_w, const float* __restrict__ dinv_1,
                            float* __restrict__ coef_w, float* __restrict__ coef_1, int E) {
    int e = blockIdx.x * 256 + threadIdx.x;
    if (e < E) {
        int s = src[e], d = dst[e];
        coef_w[e] = dinv_w[s] * w[e] * dinv_w[d];
        coef_1[e] = dinv_1[s] * dinv_1[d];
    }
}

// ---------------- GEMM: H = act(X) @ W (+bias)(+relu) ----------------
template<int K, int DOUT, bool RELU_IN, bool BIAS, bool RELU_OUT>
__global__ void gemm_kernel(const float* __restrict__ X, const float* __restrict__ W,
                            const float* __restrict__ b, float* __restrict__ H, int N) {
    constexpr int CG = DOUT / 4;             // colgroups of 4
    constexpr int RPB = (256 / CG) * 4;      // rows per block
    int tx = threadIdx.x % CG;
    int ty = threadIdx.x / CG;
    int row0 = blockIdx.x * RPB + ty * 4;
    int col0 = tx * 4;

    float acc[4][4] = {};
    for (int k = 0; k < K; k += 4) {
        float4 w0 = *reinterpret_cast<const float4*>(&W[(k + 0) * DOUT + col0]);
        float4 w1 = *reinterpret_cast<const float4*>(&W[(k + 1) * DOUT + col0]);
        float4 w2 = *reinterpret_cast<const float4*>(&W[(k + 2) * DOUT + col0]);
        float4 w3 = *reinterpret_cast<const float4*>(&W[(k + 3) * DOUT + col0]);
#pragma unroll
        for (int r = 0; r < 4; ++r) {
            int row = row0 + r;
            if (row < N) {
                float4 x4 = *reinterpret_cast<const float4*>(&X[row * K + k]);
                if constexpr (RELU_IN) {
                    x4.x = fmaxf(x4.x, 0.0f); x4.y = fmaxf(x4.y, 0.0f);
                    x4.z = fmaxf(x4.z, 0.0f); x4.w = fmaxf(x4.w, 0.0f);
                }
                acc[r][0] += x4.x * w0.x + x4.y * w1.x + x4.z * w2.x + x4.w * w3.x;
                acc[r][1] += x4.x * w0.y + x4.y * w1.y + x4.z * w2.y + x4.w * w3.y;
                acc[r][2] += x4.x * w0.z + x4.y * w1.z + x4.z * w2.z + x4.w * w3.z;
                acc[r][3] += x4.x * w0.w + x4.y * w1.w + x4.z * w2.w + x4.w * w3.w;
            }
        }
    }
    float4 bv = make_float4(0.f, 0.f, 0.f, 0.f);
    if constexpr (BIAS) bv = *reinterpret_cast<const float4*>(&b[col0]);
#pragma unroll
    for (int r = 0; r < 4; ++r) {
        int row = row0 + r;
        if (row < N) {
            float4 o = make_float4(acc[r][0] + bv.x, acc[r][1] + bv.y,
                                   acc[r][2] + bv.z, acc[r][3] + bv.w);
            if constexpr (RELU_OUT) {
                o.x = fmaxf(o.x, 0.f); o.y = fmaxf(o.y, 0.f);
                o.z = fmaxf(o.z, 0.f); o.w = fmaxf(o.w, 0.f);
            }
            *reinterpret_cast<float4*>(&H[row * DOUT + col0]) = o;
        }
    }
}

// ---------------- out = H * dinv^2 (+ b)  (self-loop init) ----------------
template<int LOGD, bool BIAS>
__global__ void init_out_kernel(const float* __restrict__ H, const float* __restrict__ dinv,
                                const float* __restrict__ b, float* __restrict__ out, int N) {
    constexpr int D = 1 << LOGD;
    int i = blockIdx.x * 256 + threadIdx.x;
    if (i < N * D) {
        int row = i >> LOGD;
        float di = dinv[row];
        float v = H[i] * di * di;
        if constexpr (BIAS) v += b[i & (D - 1)];
        out[i] = v;
    }
}

// ---------------- edge scatter: out[dst] += H[src] * coef  (float4 gather) ----------------
template<int LOGD>   // D = 1<<LOGD; D/4 threads per edge
__global__ void scatter4_kernel(const int* __restrict__ src, const int* __restrict__ dst,
                                const float* __restrict__ coef, const float* __restrict__ H,
                                float* __restrict__ out, int E) {
    constexpr int TPE = (1 << LOGD) / 4;
    int t = blockIdx.x * 256 + threadIdx.x;
    int e = t / TPE;
    int q = t % TPE;
    if (e < E) {
        int s = src[e], d = dst[e];
        float c = coef[e];
        float4 h4 = *reinterpret_cast<const float4*>(&H[(s << LOGD) + q * 4]);
        float* o = &out[(d << LOGD) + q * 4];
        atomicAdd(o + 0, h4.x * c);
        atomicAdd(o + 1, h4.y * c);
        atomicAdd(o + 2, h4.z * c);
        atomicAdd(o + 3, h4.w * c);
    }
}

__global__ void relu_kernel(float* __restrict__ p, int n) {
    int i = blockIdx.x * 256 + threadIdx.x;
    if (i < n) p[i] = fmaxf(p[i], 0.0f);
}

// ---------------- launch ----------------

extern "C" void kernel_launch(void* const* d_in, const int* in_sizes, int n_in,
                              void* d_out, int out_size, void* d_ws, size_t ws_size,
                              hipStream_t stream) {
    const float* x  = (const float*)d_in[0];
    const int*   ei = (const int*)d_in[1];
    const float* w  = (const float*)d_in[2];
    const float* W1 = (const float*)d_in[3];
    const float* b1 = (const float*)d_in[4];
    const float* W2 = (const float*)d_in[5];
    const float* b2 = (const float*)d_in[6];
    const float* W3 = (const float*)d_in[7];
    const float* b3 = (const float*)d_in[8];
    const float* W4 = (const float*)d_in[9];
    const float* b4 = (const float*)d_in[10];

    const int* src = ei;            // edge_index[0]
    const int* dst = ei + EE;       // edge_index[1]

    const int N = NN, E = EE;

    // workspace layout (floats)
    float* ws     = (float*)d_ws;
    float* dinv_w = ws;                       // N (pad 50176)
    float* dinv_1 = ws + 50176;               // N
    float* coef_w = ws + 100352;              // E
    float* coef_1 = ws + 900352;              // E
    float* g1     = ws + 1700352;             // N*64  (pre-agg h1; reused as dbuf later)
    float* h1a    = ws + 4900352;             // N*64  (aggregated h1, pre-relu)
    float* g2     = ws + 8100352;             // N*32
    float* p3     = ws + 9700352;             // N*32
    float* p4     = ws + 11300352;            // N*64  (end: 14,500,352 floats = 58 MB)
    float* dbuf   = g1;                       // g1 dead after L1 scatter + L2 gemm

    float* recon = (float*)d_out;             // N*256
    float* zout  = (float*)d_out + NN * 256;  // N*32

    // ---- normalization ----
    hipMemsetAsync(dinv_w, 0, N * sizeof(float), stream);
    hipMemsetAsync(dinv_1, 0, N * sizeof(float), stream);
    deg_kernel<<<(E + 255) / 256, 256, 0, stream>>>(dst, w, dinv_w, dinv_1, E);
    dinv_kernel<<<(N + 255) / 256, 256, 0, stream>>>(dinv_w, dinv_1, N);
    coef_kernel<<<(E + 255) / 256, 256, 0, stream>>>(src, dst, w, dinv_w, dinv_1,
                                                     coef_w, coef_1, E);

    // ---- layer 1: h1 = relu(prop_w(x@W1) + b1)   [relu deferred into L2 gemm] ----
    gemm_kernel<256, 64, false, false, false><<<(N + 63) / 64, 256, 0, stream>>>(x, W1, nullptr, g1, N);
    init_out_kernel<6, true><<<(N * 64 + 255) / 256, 256, 0, stream>>>(g1, dinv_w, b1, h1a, N);
    scatter4_kernel<6><<<(E * 16 + 255) / 256, 256, 0, stream>>>(src, dst, coef_w, g1, h1a, E);

    // ---- layer 2: z = relu(prop_w(h1@W2) + b2) -> zout (output) ----
    gemm_kernel<64, 32, true, false, false><<<(N + 127) / 128, 256, 0, stream>>>(h1a, W2, nullptr, g2, N);
    init_out_kernel<5, true><<<(N * 32 + 255) / 256, 256, 0, stream>>>(g2, dinv_w, b2, zout, N);
    scatter4_kernel<5><<<(E * 8 + 255) / 256, 256, 0, stream>>>(src, dst, coef_w, g2, zout, E);
    relu_kernel<<<(N * 32 + 255) / 256, 256, 0, stream>>>(zout, N * 32);

    // ---- layer 3: d = relu(prop_w(z) @ W3 + b3)   (propagate in 32-dim space) ----
    init_out_kernel<5, false><<<(N * 32 + 255) / 256, 256, 0, stream>>>(zout, dinv_w, nullptr, p3, N);
    scatter4_kernel<5><<<(E * 8 + 255) / 256, 256, 0, stream>>>(src, dst, coef_w, zout, p3, E);
    gemm_kernel<32, 64, false, true, true><<<(N + 63) / 64, 256, 0, stream>>>(p3, W3, b3, dbuf, N);

    // ---- layer 4: recon = prop_1(d) @ W4 + b4     (propagate in 64-dim space) ----
    init_out_kernel<6, false><<<(N * 64 + 255) / 256, 256, 0, stream>>>(dbuf, dinv_1, nullptr, p4, N);
    scatter4_kernel<6><<<(E * 16 + 255) / 256, 256, 0, stream>>>(src, dst, coef_1, dbuf, p4, E);
    gemm_kernel<64, 256, false, true, false><<<(N + 15) / 16, 256, 0, stream>>>(p4, W4, b4, recon, N);

    (void)in_sizes; (void)n_in; (void)out_size; (void)ws_size;
}

// Round 4
// 561.004 us; speedup vs baseline: 6.0900x; 4.1466x over previous
//
#include <hip/hip_runtime.h>

#define NN 50000
#define EE 800000

// ---------------- degree histogram ----------------
__global__ void deg_kernel(const int* __restrict__ dst, const float* __restrict__ w,
                           float* __restrict__ deg_w, int* __restrict__ counts, int E) {
    int e = blockIdx.x * 256 + threadIdx.x;
    if (e < E) {
        int d = dst[e];
        atomicAdd(&deg_w[d], w[e]);
        atomicAdd(&counts[d], 1);
    }
}

__global__ void dinv_kernel(float* __restrict__ dinv_w, float* __restrict__ dinv_1,
                            const int* __restrict__ counts, int N) {
    int i = blockIdx.x * 256 + threadIdx.x;
    if (i < N) {
        dinv_w[i] = rsqrtf(dinv_w[i] + 1.0f);           // in-place deg_w -> D^-1/2
        dinv_1[i] = rsqrtf((float)counts[i] + 1.0f);
    }
}

// ---------------- exclusive scan of counts -> row_off ----------------
__global__ void scan_block_kernel(const int* __restrict__ counts, int* __restrict__ row_off,
                                  int* __restrict__ bsum, int N) {
    __shared__ int tmp[256];
    int i = blockIdx.x * 256 + threadIdx.x;
    int v = (i < N) ? counts[i] : 0;
    tmp[threadIdx.x] = v;
    __syncthreads();
    for (int off = 1; off < 256; off <<= 1) {
        int t = (threadIdx.x >= off) ? tmp[threadIdx.x - off] : 0;
        __syncthreads();
        tmp[threadIdx.x] += t;
        __syncthreads();
    }
    if (i < N) row_off[i] = tmp[threadIdx.x] - v;   // exclusive within block
    if (threadIdx.x == 255) bsum[blockIdx.x] = tmp[255];
}

__global__ void scan_bsum_kernel(int* __restrict__ bsum, int nb) {
    __shared__ int tmp[256];
    int v = (threadIdx.x < nb) ? bsum[threadIdx.x] : 0;
    tmp[threadIdx.x] = v;
    __syncthreads();
    for (int off = 1; off < 256; off <<= 1) {
        int t = (threadIdx.x >= off) ? tmp[threadIdx.x - off] : 0;
        __syncthreads();
        tmp[threadIdx.x] += t;
        __syncthreads();
    }
    if (threadIdx.x < nb) bsum[threadIdx.x] = tmp[threadIdx.x] - v;  // exclusive
}

__global__ void scan_add_kernel(int* __restrict__ row_off, const int* __restrict__ bsum,
                                int* __restrict__ pos, int N, int E) {
    int i = blockIdx.x * 256 + threadIdx.x;
    if (i < N) {
        int r = row_off[i] + bsum[i >> 8];
        row_off[i] = r;
        pos[i] = r;                 // running cursor for the fill pass
    }
    if (i == 0) row_off[N] = E;
}

// ---------------- CSR fill: dst-binned src + precomputed coefficients ----------------
__global__ void fill_kernel(const int* __restrict__ src, const int* __restrict__ dst,
                            const float* __restrict__ w,
                            const float* __restrict__ dinv_w, const float* __restrict__ dinv_1,
                            int* __restrict__ pos, int* __restrict__ srcS,
                            float* __restrict__ coefwS, float* __restrict__ coef1S, int E) {
    int e = blockIdx.x * 256 + threadIdx.x;
    if (e < E) {
        int s = src[e], d = dst[e];
        int p = atomicAdd(&pos[d], 1);
        srcS[p] = s;
        coefwS[p] = dinv_w[s] * w[e] * dinv_w[d];
        coef1S[p] = dinv_1[s] * dinv_1[d];
    }
}

// ---------------- GEMM: H = X @ W (+bias)(+relu) ----------------
template<int K, int DOUT, bool BIAS, bool RELU_OUT>
__global__ void gemm_kernel(const float* __restrict__ X, const float* __restrict__ W,
                            const float* __restrict__ b, float* __restrict__ H, int N) {
    constexpr int CG = DOUT / 4;             // colgroups of 4
    constexpr int RPB = (256 / CG) * 4;      // rows per block
    int tx = threadIdx.x % CG;
    int ty = threadIdx.x / CG;
    int row0 = blockIdx.x * RPB + ty * 4;
    int col0 = tx * 4;

    float acc[4][4] = {};
    for (int k = 0; k < K; k += 4) {
        float4 w0 = *reinterpret_cast<const float4*>(&W[(k + 0) * DOUT + col0]);
        float4 w1 = *reinterpret_cast<const float4*>(&W[(k + 1) * DOUT + col0]);
        float4 w2 = *reinterpret_cast<const float4*>(&W[(k + 2) * DOUT + col0]);
        float4 w3 = *reinterpret_cast<const float4*>(&W[(k + 3) * DOUT + col0]);
#pragma unroll
        for (int r = 0; r < 4; ++r) {
            int row = row0 + r;
            if (row < N) {
                float4 x4 = *reinterpret_cast<const float4*>(&X[row * K + k]);
                acc[r][0] += x4.x * w0.x + x4.y * w1.x + x4.z * w2.x + x4.w * w3.x;
                acc[r][1] += x4.x * w0.y + x4.y * w1.y + x4.z * w2.y + x4.w * w3.y;
                acc[r][2] += x4.x * w0.z + x4.y * w1.z + x4.z * w2.z + x4.w * w3.z;
                acc[r][3] += x4.x * w0.w + x4.y * w1.w + x4.z * w2.w + x4.w * w3.w;
            }
        }
    }
    float4 bv = make_float4(0.f, 0.f, 0.f, 0.f);
    if constexpr (BIAS) bv = *reinterpret_cast<const float4*>(&b[col0]);
#pragma unroll
    for (int r = 0; r < 4; ++r) {
        int row = row0 + r;
        if (row < N) {
            float4 o = make_float4(acc[r][0] + bv.x, acc[r][1] + bv.y,
                                   acc[r][2] + bv.z, acc[r][3] + bv.w);
            if constexpr (RELU_OUT) {
                o.x = fmaxf(o.x, 0.f); o.y = fmaxf(o.y, 0.f);
                o.z = fmaxf(o.z, 0.f); o.w = fmaxf(o.w, 0.f);
            }
            *reinterpret_cast<float4*>(&H[row * DOUT + col0]) = o;
        }
    }
}

// ---------------- pull aggregation (zero atomics) ----------------
// out[n,f] = sum_{j in row n} H[srcS[j],f]*coef[j] + H[n,f]*dinv[n]^2 (+b[f]) (relu)
// D=64: one wave per node, lane = feature.
template<bool BIAS, bool RELU>
__global__ void pull64_kernel(const int* __restrict__ row_off, const int* __restrict__ srcS,
                              const float* __restrict__ coefS, const float* __restrict__ H,
                              const float* __restrict__ dinv, const float* __restrict__ b,
                              float* __restrict__ out, int N) {
    int node = blockIdx.x * 4 + (threadIdx.x >> 6);
    int f = threadIdx.x & 63;
    if (node >= N) return;
    int beg = row_off[node], end = row_off[node + 1];
    float acc = 0.0f;
    for (int j = beg; j < end; ++j) {
        acc += H[srcS[j] * 64 + f] * coefS[j];
    }
    float di = dinv[node];
    float v = acc + H[node * 64 + f] * di * di;
    if constexpr (BIAS) v += b[f];
    if constexpr (RELU) v = fmaxf(v, 0.0f);
    out[node * 64 + f] = v;
}

// D=32: half-wave per node (8 nodes per 256-block), lane&31 = feature. No shuffles.
template<bool BIAS, bool RELU>
__global__ void pull32_kernel(const int* __restrict__ row_off, const int* __restrict__ srcS,
                              const float* __restrict__ coefS, const float* __restrict__ H,
                              const float* __restrict__ dinv, const float* __restrict__ b,
                              float* __restrict__ out, float* __restrict__ out2, int N) {
    int node = blockIdx.x * 8 + (threadIdx.x >> 5);
    int f = threadIdx.x & 31;
    if (node >= N) return;
    int beg = row_off[node], end = row_off[node + 1];
    float acc = 0.0f;
    for (int j = beg; j < end; ++j) {
        acc += H[srcS[j] * 32 + f] * coefS[j];
    }
    float di = dinv[node];
    float v = acc + H[node * 32 + f] * di * di;
    if constexpr (BIAS) v += b[f];
    if constexpr (RELU) v = fmaxf(v, 0.0f);
    out[node * 32 + f] = v;
    if (out2) out2[node * 32 + f] = v;
}

// ---------------- launch ----------------

extern "C" void kernel_launch(void* const* d_in, const int* in_sizes, int n_in,
                              void* d_out, int out_size, void* d_ws, size_t ws_size,
                              hipStream_t stream) {
    const float* x  = (const float*)d_in[0];
    const int*   ei = (const int*)d_in[1];
    const float* w  = (const float*)d_in[2];
    const float* W1 = (const float*)d_in[3];
    const float* b1 = (const float*)d_in[4];
    const float* W2 = (const float*)d_in[5];
    const float* b2 = (const float*)d_in[6];
    const float* W3 = (const float*)d_in[7];
    const float* b3 = (const float*)d_in[8];
    const float* W4 = (const float*)d_in[9];
    const float* b4 = (const float*)d_in[10];

    const int* src = ei;            // edge_index[0]
    const int* dst = ei + EE;       // edge_index[1]

    const int N = NN, E = EE;
    const int NB = (N + 255) / 256;         // 196 scan blocks

    // workspace layout (4-byte words), total 81.0 MB (< R1-proven 83.6 MB)
    float* ws     = (float*)d_ws;
    float* dinv_w = ws;                       // N (pad 50176)
    float* dinv_1 = ws + 50176;               // N
    int*   counts = (int*)(ws + 100352);      // N
    int*   row_off= (int*)(ws + 150528);      // N+1
    int*   pos    = (int*)(ws + 200704);      // N
    int*   bsum   = (int*)(ws + 250880);      // 256
    int*   srcS   = (int*)(ws + 251136);      // E
    float* coefwS = ws + 1051136;             // E
    float* coef1S = ws + 1851136;             // E
    float* g1     = ws + 2651136;             // N*64
    float* h1     = ws + 5851136;             // N*64
    float* g2     = ws + 9051136;             // N*32
    float* zws    = ws + 10651136;            // N*32  (z kept in ws; d_out copy separate)
    float* p3     = ws + 12251136;            // N*32
    float* dbuf   = ws + 13851136;            // N*64
    float* p4     = ws + 17051136;            // N*64  (end 20,251,136 words)

    float* recon = (float*)d_out;             // N*256
    float* zout  = (float*)d_out + NN * 256;  // N*32

    // ---- normalization + CSR build ----
    hipMemsetAsync(dinv_w, 0, N * sizeof(float), stream);
    hipMemsetAsync(counts, 0, N * sizeof(int), stream);
    deg_kernel<<<(E + 255) / 256, 256, 0, stream>>>(dst, w, dinv_w, counts, E);
    dinv_kernel<<<NB, 256, 0, stream>>>(dinv_w, dinv_1, counts, N);
    scan_block_kernel<<<NB, 256, 0, stream>>>(counts, row_off, bsum, N);
    scan_bsum_kernel<<<1, 256, 0, stream>>>(bsum, NB);
    scan_add_kernel<<<NB, 256, 0, stream>>>(row_off, bsum, pos, N, E);
    fill_kernel<<<(E + 255) / 256, 256, 0, stream>>>(src, dst, w, dinv_w, dinv_1,
                                                     pos, srcS, coefwS, coef1S, E);

    // ---- layer 1: h1 = relu(prop_w(x@W1) + b1) ----
    gemm_kernel<256, 64, false, false><<<(N + 63) / 64, 256, 0, stream>>>(x, W1, nullptr, g1, N);
    pull64_kernel<true, true><<<(N + 3) / 4, 256, 0, stream>>>(row_off, srcS, coefwS, g1, dinv_w, b1, h1, N);

    // ---- layer 2: z = relu(prop_w(h1@W2) + b2) -> zws (+ copy to zout) ----
    gemm_kernel<64, 32, false, false><<<(N + 127) / 128, 256, 0, stream>>>(h1, W2, nullptr, g2, N);
    pull32_kernel<true, true><<<(N + 7) / 8, 256, 0, stream>>>(row_off, srcS, coefwS, g2, dinv_w, b2, zws, zout, N);

    // ---- layer 3: d = relu(prop_w(z) @ W3 + b3)   (propagate in 32-dim space) ----
    pull32_kernel<false, false><<<(N + 7) / 8, 256, 0, stream>>>(row_off, srcS, coefwS, zws, dinv_w, nullptr, p3, nullptr, N);
    gemm_kernel<32, 64, true, true><<<(N + 63) / 64, 256, 0, stream>>>(p3, W3, b3, dbuf, N);

    // ---- layer 4: recon = prop_1(d) @ W4 + b4     (propagate in 64-dim space) ----
    pull64_kernel<false, false><<<(N + 3) / 4, 256, 0, stream>>>(row_off, srcS, coef1S, dbuf, dinv_1, nullptr, p4, N);
    gemm_kernel<64, 256, true, false><<<(N + 15) / 16, 256, 0, stream>>>(p4, W4, b4, recon, N);

    (void)in_sizes; (void)n_in; (void)out_size; (void)ws_size;
}

// Round 5
// 469.548 us; speedup vs baseline: 7.2761x; 1.1948x over previous
//
#include <hip/hip_runtime.h>

#define NN 50000
#define EE 800000

// ---------------- degree histogram ----------------
__global__ void deg_kernel(const int* __restrict__ dst, const float* __restrict__ w,
                           float* __restrict__ deg_w, int* __restrict__ counts, int E) {
    int e = blockIdx.x * 256 + threadIdx.x;
    if (e < E) {
        int d = dst[e];
        atomicAdd(&deg_w[d], w[e]);
        atomicAdd(&counts[d], 1);
    }
}

__global__ void dinv_kernel(float* __restrict__ dinv_w, float* __restrict__ dinv_1,
                            const int* __restrict__ counts, int N) {
    int i = blockIdx.x * 256 + threadIdx.x;
    if (i < N) {
        dinv_w[i] = rsqrtf(dinv_w[i] + 1.0f);           // in-place deg_w -> D^-1/2
        dinv_1[i] = rsqrtf((float)counts[i] + 1.0f);
    }
}

// ---------------- exclusive scan of counts -> row_off ----------------
__global__ void scan_block_kernel(const int* __restrict__ counts, int* __restrict__ row_off,
                                  int* __restrict__ bsum, int N) {
    __shared__ int tmp[256];
    int i = blockIdx.x * 256 + threadIdx.x;
    int v = (i < N) ? counts[i] : 0;
    tmp[threadIdx.x] = v;
    __syncthreads();
    for (int off = 1; off < 256; off <<= 1) {
        int t = (threadIdx.x >= off) ? tmp[threadIdx.x - off] : 0;
        __syncthreads();
        tmp[threadIdx.x] += t;
        __syncthreads();
    }
    if (i < N) row_off[i] = tmp[threadIdx.x] - v;   // exclusive within block
    if (threadIdx.x == 255) bsum[blockIdx.x] = tmp[255];
}

__global__ void scan_bsum_kernel(int* __restrict__ bsum, int nb) {
    __shared__ int tmp[256];
    int v = (threadIdx.x < nb) ? bsum[threadIdx.x] : 0;
    tmp[threadIdx.x] = v;
    __syncthreads();
    for (int off = 1; off < 256; off <<= 1) {
        int t = (threadIdx.x >= off) ? tmp[threadIdx.x - off] : 0;
        __syncthreads();
        tmp[threadIdx.x] += t;
        __syncthreads();
    }
    if (threadIdx.x < nb) bsum[threadIdx.x] = tmp[threadIdx.x] - v;  // exclusive
}

__global__ void scan_add_kernel(int* __restrict__ row_off, const int* __restrict__ bsum,
                                int* __restrict__ pos, int N, int E) {
    int i = blockIdx.x * 256 + threadIdx.x;
    if (i < N) {
        int r = row_off[i] + bsum[i >> 8];
        row_off[i] = r;
        pos[i] = r;                 // running cursor for the fill pass
    }
    if (i == 0) row_off[N] = E;
}

// ---------------- CSR fill: dst-binned src + precomputed coefficients ----------------
__global__ void fill_kernel(const int* __restrict__ src, const int* __restrict__ dst,
                            const float* __restrict__ w,
                            const float* __restrict__ dinv_w, const float* __restrict__ dinv_1,
                            int* __restrict__ pos, int* __restrict__ srcS,
                            float* __restrict__ coefwS, float* __restrict__ coef1S, int E) {
    int e = blockIdx.x * 256 + threadIdx.x;
    if (e < E) {
        int s = src[e], d = dst[e];
        int p = atomicAdd(&pos[d], 1);
        srcS[p] = s;
        coefwS[p] = dinv_w[s] * w[e] * dinv_w[d];
        coef1S[p] = dinv_1[s] * dinv_1[d];
    }
}

// ---------------- LDS-tiled GEMM: H = X @ W (+bias)(+relu) ----------------
// BM=64, BN=64, BK=16, 256 threads, 4x4 register blocking.
// grid.x = row tiles, grid.y = DOUT/64 col tiles.
template<int K, int DOUT, bool BIAS, bool RELU_OUT>
__global__ __launch_bounds__(256) void tgemm_kernel(const float* __restrict__ X,
                                                    const float* __restrict__ W,
                                                    const float* __restrict__ b,
                                                    float* __restrict__ H, int N) {
    constexpr int BK = 16;
    __shared__ float Xs[BK][68];   // [k][row], pad 68 -> <=2-way bank aliasing, 16B-aligned rows
    __shared__ float Ws[BK][68];   // [k][col]

    const int t = threadIdx.x;
    const int tx = t & 15;         // col group (4 cols)
    const int ty = t >> 4;         // row group (4 rows)
    const int brow = blockIdx.x * 64;
    const int bcol = blockIdx.y * 64;

    // staging coordinates
    const int row_l = t >> 2;      // 0..63
    const int kq    = t & 3;       // 0..3 (quad of k)
    int srow = brow + row_l;
    if (srow > N - 1) srow = N - 1;          // clamp tail (duplicate loads, stores guarded)

    float acc[4][4] = {};

    for (int kc = 0; kc < K; kc += BK) {
        // stage X tile (64 rows x 16 k), transposed into Xs[k][row]
        float4 xv = *reinterpret_cast<const float4*>(&X[srow * K + kc + kq * 4]);
        Xs[kq * 4 + 0][row_l] = xv.x;
        Xs[kq * 4 + 1][row_l] = xv.y;
        Xs[kq * 4 + 2][row_l] = xv.z;
        Xs[kq * 4 + 3][row_l] = xv.w;
        // stage W tile (16 k x 64 cols)
        float4 wv = *reinterpret_cast<const float4*>(&W[(kc + ty) * DOUT + bcol + tx * 4]);
        *reinterpret_cast<float4*>(&Ws[ty][tx * 4]) = wv;
        __syncthreads();

#pragma unroll
        for (int kk = 0; kk < BK; ++kk) {
            float4 a = *reinterpret_cast<const float4*>(&Xs[kk][ty * 4]);
            float4 wr = *reinterpret_cast<const float4*>(&Ws[kk][tx * 4]);
            acc[0][0] += a.x * wr.x; acc[0][1] += a.x * wr.y; acc[0][2] += a.x * wr.z; acc[0][3] += a.x * wr.w;
            acc[1][0] += a.y * wr.x; acc[1][1] += a.y * wr.y; acc[1][2] += a.y * wr.z; acc[1][3] += a.y * wr.w;
            acc[2][0] += a.z * wr.x; acc[2][1] += a.z * wr.y; acc[2][2] += a.z * wr.z; acc[2][3] += a.z * wr.w;
            acc[3][0] += a.w * wr.x; acc[3][1] += a.w * wr.y; acc[3][2] += a.w * wr.z; acc[3][3] += a.w * wr.w;
        }
        __syncthreads();
    }

    float4 bv = make_float4(0.f, 0.f, 0.f, 0.f);
    if constexpr (BIAS) bv = *reinterpret_cast<const float4*>(&b[bcol + tx * 4]);
#pragma unroll
    for (int r = 0; r < 4; ++r) {
        int row = brow + ty * 4 + r;
        if (row < N) {
            float4 o = make_float4(acc[r][0] + bv.x, acc[r][1] + bv.y,
                                   acc[r][2] + bv.z, acc[r][3] + bv.w);
            if constexpr (RELU_OUT) {
                o.x = fmaxf(o.x, 0.f); o.y = fmaxf(o.y, 0.f);
                o.z = fmaxf(o.z, 0.f); o.w = fmaxf(o.w, 0.f);
            }
            *reinterpret_cast<float4*>(&H[row * DOUT + bcol + tx * 4]) = o;
        }
    }
}

// ---------------- simple register GEMM (small layers 2/3) ----------------
template<int K, int DOUT, bool BIAS, bool RELU_OUT>
__global__ void gemm_kernel(const float* __restrict__ X, const float* __restrict__ W,
                            const float* __restrict__ b, float* __restrict__ H, int N) {
    constexpr int CG = DOUT / 4;             // colgroups of 4
    constexpr int RPB = (256 / CG) * 4;      // rows per block
    int tx = threadIdx.x % CG;
    int ty = threadIdx.x / CG;
    int row0 = blockIdx.x * RPB + ty * 4;
    int col0 = tx * 4;

    float acc[4][4] = {};
    for (int k = 0; k < K; k += 4) {
        float4 w0 = *reinterpret_cast<const float4*>(&W[(k + 0) * DOUT + col0]);
        float4 w1 = *reinterpret_cast<const float4*>(&W[(k + 1) * DOUT + col0]);
        float4 w2 = *reinterpret_cast<const float4*>(&W[(k + 2) * DOUT + col0]);
        float4 w3 = *reinterpret_cast<const float4*>(&W[(k + 3) * DOUT + col0]);
#pragma unroll
        for (int r = 0; r < 4; ++r) {
            int row = row0 + r;
            if (row < N) {
                float4 x4 = *reinterpret_cast<const float4*>(&X[row * K + k]);
                acc[r][0] += x4.x * w0.x + x4.y * w1.x + x4.z * w2.x + x4.w * w3.x;
                acc[r][1] += x4.x * w0.y + x4.y * w1.y + x4.z * w2.y + x4.w * w3.y;
                acc[r][2] += x4.x * w0.z + x4.y * w1.z + x4.z * w2.z + x4.w * w3.z;
                acc[r][3] += x4.x * w0.w + x4.y * w1.w + x4.z * w2.w + x4.w * w3.w;
            }
        }
    }
    float4 bv = make_float4(0.f, 0.f, 0.f, 0.f);
    if constexpr (BIAS) bv = *reinterpret_cast<const float4*>(&b[col0]);
#pragma unroll
    for (int r = 0; r < 4; ++r) {
        int row = row0 + r;
        if (row < N) {
            float4 o = make_float4(acc[r][0] + bv.x, acc[r][1] + bv.y,
                                   acc[r][2] + bv.z, acc[r][3] + bv.w);
            if constexpr (RELU_OUT) {
                o.x = fmaxf(o.x, 0.f); o.y = fmaxf(o.y, 0.f);
                o.z = fmaxf(o.z, 0.f); o.w = fmaxf(o.w, 0.f);
            }
            *reinterpret_cast<float4*>(&H[row * DOUT + col0]) = o;
        }
    }
}

// ---------------- pull aggregation (zero atomics) ----------------
template<bool BIAS, bool RELU>
__global__ void pull64_kernel(const int* __restrict__ row_off, const int* __restrict__ srcS,
                              const float* __restrict__ coefS, const float* __restrict__ H,
                              const float* __restrict__ dinv, const float* __restrict__ b,
                              float* __restrict__ out, int N) {
    int node = blockIdx.x * 4 + (threadIdx.x >> 6);
    int f = threadIdx.x & 63;
    if (node >= N) return;
    int beg = row_off[node], end = row_off[node + 1];
    float acc = 0.0f;
    for (int j = beg; j < end; ++j) {
        acc += H[srcS[j] * 64 + f] * coefS[j];
    }
    float di = dinv[node];
    float v = acc + H[node * 64 + f] * di * di;
    if constexpr (BIAS) v += b[f];
    if constexpr (RELU) v = fmaxf(v, 0.0f);
    out[node * 64 + f] = v;
}

template<bool BIAS, bool RELU>
__global__ void pull32_kernel(const int* __restrict__ row_off, const int* __restrict__ srcS,
                              const float* __restrict__ coefS, const float* __restrict__ H,
                              const float* __restrict__ dinv, const float* __restrict__ b,
                              float* __restrict__ out, float* __restrict__ out2, int N) {
    int node = blockIdx.x * 8 + (threadIdx.x >> 5);
    int f = threadIdx.x & 31;
    if (node >= N) return;
    int beg = row_off[node], end = row_off[node + 1];
    float acc = 0.0f;
    for (int j = beg; j < end; ++j) {
        acc += H[srcS[j] * 32 + f] * coefS[j];
    }
    float di = dinv[node];
    float v = acc + H[node * 32 + f] * di * di;
    if constexpr (BIAS) v += b[f];
    if constexpr (RELU) v = fmaxf(v, 0.0f);
    out[node * 32 + f] = v;
    if (out2) out2[node * 32 + f] = v;
}

// ---------------- launch ----------------

extern "C" void kernel_launch(void* const* d_in, const int* in_sizes, int n_in,
                              void* d_out, int out_size, void* d_ws, size_t ws_size,
                              hipStream_t stream) {
    const float* x  = (const float*)d_in[0];
    const int*   ei = (const int*)d_in[1];
    const float* w  = (const float*)d_in[2];
    const float* W1 = (const float*)d_in[3];
    const float* b1 = (const float*)d_in[4];
    const float* W2 = (const float*)d_in[5];
    const float* b2 = (const float*)d_in[6];
    const float* W3 = (const float*)d_in[7];
    const float* b3 = (const float*)d_in[8];
    const float* W4 = (const float*)d_in[9];
    const float* b4 = (const float*)d_in[10];

    const int* src = ei;            // edge_index[0]
    const int* dst = ei + EE;       // edge_index[1]

    const int N = NN, E = EE;
    const int NB = (N + 255) / 256;         // 196 scan blocks

    // workspace layout (4-byte words), total 81.0 MB
    float* ws     = (float*)d_ws;
    float* dinv_w = ws;                       // N (pad 50176)
    float* dinv_1 = ws + 50176;               // N
    int*   counts = (int*)(ws + 100352);      // N
    int*   row_off= (int*)(ws + 150528);      // N+1
    int*   pos    = (int*)(ws + 200704);      // N
    int*   bsum   = (int*)(ws + 250880);      // 256
    int*   srcS   = (int*)(ws + 251136);      // E
    float* coefwS = ws + 1051136;             // E
    float* coef1S = ws + 1851136;             // E
    float* g1     = ws + 2651136;             // N*64
    float* h1     = ws + 5851136;             // N*64
    float* g2     = ws + 9051136;             // N*32
    float* zws    = ws + 10651136;            // N*32
    float* p3     = ws + 12251136;            // N*32
    float* dbuf   = ws + 13851136;            // N*64
    float* p4     = ws + 17051136;            // N*64  (end 20,251,136 words)

    float* recon = (float*)d_out;             // N*256
    float* zout  = (float*)d_out + NN * 256;  // N*32

    // ---- normalization + CSR build ----
    hipMemsetAsync(dinv_w, 0, N * sizeof(float), stream);
    hipMemsetAsync(counts, 0, N * sizeof(int), stream);
    deg_kernel<<<(E + 255) / 256, 256, 0, stream>>>(dst, w, dinv_w, counts, E);
    dinv_kernel<<<NB, 256, 0, stream>>>(dinv_w, dinv_1, counts, N);
    scan_block_kernel<<<NB, 256, 0, stream>>>(counts, row_off, bsum, N);
    scan_bsum_kernel<<<1, 256, 0, stream>>>(bsum, NB);
    scan_add_kernel<<<NB, 256, 0, stream>>>(row_off, bsum, pos, N, E);
    fill_kernel<<<(E + 255) / 256, 256, 0, stream>>>(src, dst, w, dinv_w, dinv_1,
                                                     pos, srcS, coefwS, coef1S, E);

    // ---- layer 1: h1 = relu(prop_w(x@W1) + b1) ----
    tgemm_kernel<256, 64, false, false><<<dim3((N + 63) / 64, 1), 256, 0, stream>>>(x, W1, nullptr, g1, N);
    pull64_kernel<true, true><<<(N + 3) / 4, 256, 0, stream>>>(row_off, srcS, coefwS, g1, dinv_w, b1, h1, N);

    // ---- layer 2: z = relu(prop_w(h1@W2) + b2) -> zws (+ copy to zout) ----
    gemm_kernel<64, 32, false, false><<<(N + 127) / 128, 256, 0, stream>>>(h1, W2, nullptr, g2, N);
    pull32_kernel<true, true><<<(N + 7) / 8, 256, 0, stream>>>(row_off, srcS, coefwS, g2, dinv_w, b2, zws, zout, N);

    // ---- layer 3: d = relu(prop_w(z) @ W3 + b3)   (propagate in 32-dim space) ----
    pull32_kernel<false, false><<<(N + 7) / 8, 256, 0, stream>>>(row_off, srcS, coefwS, zws, dinv_w, nullptr, p3, nullptr, N);
    gemm_kernel<32, 64, true, true><<<(N + 63) / 64, 256, 0, stream>>>(p3, W3, b3, dbuf, N);

    // ---- layer 4: recon = prop_1(d) @ W4 + b4     (propagate in 64-dim space) ----
    pull64_kernel<false, false><<<(N + 3) / 4, 256, 0, stream>>>(row_off, srcS, coef1S, dbuf, dinv_1, nullptr, p4, N);
    tgemm_kernel<64, 256, true, false><<<dim3((N + 63) / 64, 4), 256, 0, stream>>>(p4, W4, b4, recon, N);

    (void)in_sizes; (void)n_in; (void)out_size; (void)ws_size;
}

// Round 6
// 347.848 us; speedup vs baseline: 9.8218x; 1.3499x over previous
//
#include <hip/hip_runtime.h>

#define NN 50000
#define EE 800000

// ---------------- degree histogram ----------------
__global__ void deg_kernel(const int* __restrict__ dst, const float* __restrict__ w,
                           float* __restrict__ deg_w, int* __restrict__ counts, int E) {
    int e = blockIdx.x * 256 + threadIdx.x;
    if (e < E) {
        int d = dst[e];
        atomicAdd(&deg_w[d], w[e]);
        atomicAdd(&counts[d], 1);
    }
}

__global__ void dinv_kernel(float* __restrict__ dinv_w, float* __restrict__ dinv_1,
                            const int* __restrict__ counts, int N) {
    int i = blockIdx.x * 256 + threadIdx.x;
    if (i < N) {
        dinv_w[i] = rsqrtf(dinv_w[i] + 1.0f);           // in-place deg_w -> D^-1/2
        dinv_1[i] = rsqrtf((float)counts[i] + 1.0f);
    }
}

// ---------------- exclusive scan of counts -> row_off ----------------
__global__ void scan_block_kernel(const int* __restrict__ counts, int* __restrict__ row_off,
                                  int* __restrict__ bsum, int N) {
    __shared__ int tmp[256];
    int i = blockIdx.x * 256 + threadIdx.x;
    int v = (i < N) ? counts[i] : 0;
    tmp[threadIdx.x] = v;
    __syncthreads();
    for (int off = 1; off < 256; off <<= 1) {
        int t = (threadIdx.x >= off) ? tmp[threadIdx.x - off] : 0;
        __syncthreads();
        tmp[threadIdx.x] += t;
        __syncthreads();
    }
    if (i < N) row_off[i] = tmp[threadIdx.x] - v;   // exclusive within block
    if (threadIdx.x == 255) bsum[blockIdx.x] = tmp[255];
}

__global__ void scan_bsum_kernel(int* __restrict__ bsum, int nb) {
    __shared__ int tmp[256];
    int v = (threadIdx.x < nb) ? bsum[threadIdx.x] : 0;
    tmp[threadIdx.x] = v;
    __syncthreads();
    for (int off = 1; off < 256; off <<= 1) {
        int t = (threadIdx.x >= off) ? tmp[threadIdx.x - off] : 0;
        __syncthreads();
        tmp[threadIdx.x] += t;
        __syncthreads();
    }
    if (threadIdx.x < nb) bsum[threadIdx.x] = tmp[threadIdx.x] - v;  // exclusive
}

__global__ void scan_add_kernel(int* __restrict__ row_off, const int* __restrict__ bsum,
                                int* __restrict__ pos, int N, int E) {
    int i = blockIdx.x * 256 + threadIdx.x;
    if (i < N) {
        int r = row_off[i] + bsum[i >> 8];
        row_off[i] = r;
        pos[i] = r;                 // running cursor for the fill pass
    }
    if (i == 0) row_off[N] = E;
}

// ---------------- CSR fill: dst-binned src + precomputed coefficients ----------------
__global__ void fill_kernel(const int* __restrict__ src, const int* __restrict__ dst,
                            const float* __restrict__ w,
                            const float* __restrict__ dinv_w, const float* __restrict__ dinv_1,
                            int* __restrict__ pos, int* __restrict__ srcS,
                            float* __restrict__ coefwS, float* __restrict__ coef1S, int E) {
    int e = blockIdx.x * 256 + threadIdx.x;
    if (e < E) {
        int s = src[e], d = dst[e];
        int p = atomicAdd(&pos[d], 1);
        srcS[p] = s;
        coefwS[p] = dinv_w[s] * w[e] * dinv_w[d];
        coef1S[p] = dinv_1[s] * dinv_1[d];
    }
}

// ---------------- LDS-tiled GEMM: H = X @ W (+bias)(+relu) ----------------
template<int K, int DOUT, bool BIAS, bool RELU_OUT>
__global__ __launch_bounds__(256) void tgemm_kernel(const float* __restrict__ X,
                                                    const float* __restrict__ W,
                                                    const float* __restrict__ b,
                                                    float* __restrict__ H, int N) {
    constexpr int BK = 16;
    __shared__ float Xs[BK][68];
    __shared__ float Ws[BK][68];

    const int t = threadIdx.x;
    const int tx = t & 15;
    const int ty = t >> 4;
    const int brow = blockIdx.x * 64;
    const int bcol = blockIdx.y * 64;

    const int row_l = t >> 2;
    const int kq    = t & 3;
    int srow = brow + row_l;
    if (srow > N - 1) srow = N - 1;

    float acc[4][4] = {};

    for (int kc = 0; kc < K; kc += BK) {
        float4 xv = *reinterpret_cast<const float4*>(&X[srow * K + kc + kq * 4]);
        Xs[kq * 4 + 0][row_l] = xv.x;
        Xs[kq * 4 + 1][row_l] = xv.y;
        Xs[kq * 4 + 2][row_l] = xv.z;
        Xs[kq * 4 + 3][row_l] = xv.w;
        float4 wv = *reinterpret_cast<const float4*>(&W[(kc + ty) * DOUT + bcol + tx * 4]);
        *reinterpret_cast<float4*>(&Ws[ty][tx * 4]) = wv;
        __syncthreads();

#pragma unroll
        for (int kk = 0; kk < BK; ++kk) {
            float4 a = *reinterpret_cast<const float4*>(&Xs[kk][ty * 4]);
            float4 wr = *reinterpret_cast<const float4*>(&Ws[kk][tx * 4]);
            acc[0][0] += a.x * wr.x; acc[0][1] += a.x * wr.y; acc[0][2] += a.x * wr.z; acc[0][3] += a.x * wr.w;
            acc[1][0] += a.y * wr.x; acc[1][1] += a.y * wr.y; acc[1][2] += a.y * wr.z; acc[1][3] += a.y * wr.w;
            acc[2][0] += a.z * wr.x; acc[2][1] += a.z * wr.y; acc[2][2] += a.z * wr.z; acc[2][3] += a.z * wr.w;
            acc[3][0] += a.w * wr.x; acc[3][1] += a.w * wr.y; acc[3][2] += a.w * wr.z; acc[3][3] += a.w * wr.w;
        }
        __syncthreads();
    }

    float4 bv = make_float4(0.f, 0.f, 0.f, 0.f);
    if constexpr (BIAS) bv = *reinterpret_cast<const float4*>(&b[bcol + tx * 4]);
#pragma unroll
    for (int r = 0; r < 4; ++r) {
        int row = brow + ty * 4 + r;
        if (row < N) {
            float4 o = make_float4(acc[r][0] + bv.x, acc[r][1] + bv.y,
                                   acc[r][2] + bv.z, acc[r][3] + bv.w);
            if constexpr (RELU_OUT) {
                o.x = fmaxf(o.x, 0.f); o.y = fmaxf(o.y, 0.f);
                o.z = fmaxf(o.z, 0.f); o.w = fmaxf(o.w, 0.f);
            }
            *reinterpret_cast<float4*>(&H[row * DOUT + bcol + tx * 4]) = o;
        }
    }
}

// ---------------- simple register GEMM (small layers 2/3) ----------------
template<int K, int DOUT, bool BIAS, bool RELU_OUT>
__global__ void gemm_kernel(const float* __restrict__ X, const float* __restrict__ W,
                            const float* __restrict__ b, float* __restrict__ H, int N) {
    constexpr int CG = DOUT / 4;
    constexpr int RPB = (256 / CG) * 4;
    int tx = threadIdx.x % CG;
    int ty = threadIdx.x / CG;
    int row0 = blockIdx.x * RPB + ty * 4;
    int col0 = tx * 4;

    float acc[4][4] = {};
    for (int k = 0; k < K; k += 4) {
        float4 w0 = *reinterpret_cast<const float4*>(&W[(k + 0) * DOUT + col0]);
        float4 w1 = *reinterpret_cast<const float4*>(&W[(k + 1) * DOUT + col0]);
        float4 w2 = *reinterpret_cast<const float4*>(&W[(k + 2) * DOUT + col0]);
        float4 w3 = *reinterpret_cast<const float4*>(&W[(k + 3) * DOUT + col0]);
#pragma unroll
        for (int r = 0; r < 4; ++r) {
            int row = row0 + r;
            if (row < N) {
                float4 x4 = *reinterpret_cast<const float4*>(&X[row * K + k]);
                acc[r][0] += x4.x * w0.x + x4.y * w1.x + x4.z * w2.x + x4.w * w3.x;
                acc[r][1] += x4.x * w0.y + x4.y * w1.y + x4.z * w2.y + x4.w * w3.y;
                acc[r][2] += x4.x * w0.z + x4.y * w1.z + x4.z * w2.z + x4.w * w3.z;
                acc[r][3] += x4.x * w0.w + x4.y * w1.w + x4.z * w2.w + x4.w * w3.w;
            }
        }
    }
    float4 bv = make_float4(0.f, 0.f, 0.f, 0.f);
    if constexpr (BIAS) bv = *reinterpret_cast<const float4*>(&b[col0]);
#pragma unroll
    for (int r = 0; r < 4; ++r) {
        int row = row0 + r;
        if (row < N) {
            float4 o = make_float4(acc[r][0] + bv.x, acc[r][1] + bv.y,
                                   acc[r][2] + bv.z, acc[r][3] + bv.w);
            if constexpr (RELU_OUT) {
                o.x = fmaxf(o.x, 0.f); o.y = fmaxf(o.y, 0.f);
                o.z = fmaxf(o.z, 0.f); o.w = fmaxf(o.w, 0.f);
            }
            *reinterpret_cast<float4*>(&H[row * DOUT + col0]) = o;
        }
    }
}

// ---------------- pull aggregation (zero atomics, 4-wide unrolled gathers) ----------------
// out[n,f] = sum_{j in row n} H[srcS[j],f]*coef[j] + H[n,f]*dinv[n]^2 (+b[f]) (relu)
template<bool BIAS, bool RELU>
__global__ void pull64_kernel(const int* __restrict__ row_off, const int* __restrict__ srcS,
                              const float* __restrict__ coefS, const float* __restrict__ H,
                              const float* __restrict__ dinv, const float* __restrict__ b,
                              float* __restrict__ out, int N) {
    int node = blockIdx.x * 4 + (threadIdx.x >> 6);
    int f = threadIdx.x & 63;
    if (node >= N) return;
    int beg = row_off[node], end = row_off[node + 1];
    float acc0 = 0.0f, acc1 = 0.0f, acc2 = 0.0f, acc3 = 0.0f;
    int j = beg;
    int end4 = beg + ((end - beg) & ~3);
    for (; j < end4; j += 4) {
        int s0 = srcS[j + 0], s1 = srcS[j + 1], s2 = srcS[j + 2], s3 = srcS[j + 3];
        float c0 = coefS[j + 0], c1 = coefS[j + 1], c2 = coefS[j + 2], c3 = coefS[j + 3];
        float h0 = H[s0 * 64 + f];
        float h1 = H[s1 * 64 + f];
        float h2 = H[s2 * 64 + f];
        float h3 = H[s3 * 64 + f];
        acc0 += h0 * c0; acc1 += h1 * c1; acc2 += h2 * c2; acc3 += h3 * c3;
    }
    for (; j < end; ++j) acc0 += H[srcS[j] * 64 + f] * coefS[j];
    float acc = (acc0 + acc1) + (acc2 + acc3);
    float di = dinv[node];
    float v = acc + H[node * 64 + f] * di * di;
    if constexpr (BIAS) v += b[f];
    if constexpr (RELU) v = fmaxf(v, 0.0f);
    out[node * 64 + f] = v;
}

template<bool BIAS, bool RELU>
__global__ void pull32_kernel(const int* __restrict__ row_off, const int* __restrict__ srcS,
                              const float* __restrict__ coefS, const float* __restrict__ H,
                              const float* __restrict__ dinv, const float* __restrict__ b,
                              float* __restrict__ out, float* __restrict__ out2, int N) {
    int node = blockIdx.x * 8 + (threadIdx.x >> 5);
    int f = threadIdx.x & 31;
    if (node >= N) return;
    int beg = row_off[node], end = row_off[node + 1];
    float acc0 = 0.0f, acc1 = 0.0f, acc2 = 0.0f, acc3 = 0.0f;
    int j = beg;
    int end4 = beg + ((end - beg) & ~3);
    for (; j < end4; j += 4) {
        int s0 = srcS[j + 0], s1 = srcS[j + 1], s2 = srcS[j + 2], s3 = srcS[j + 3];
        float c0 = coefS[j + 0], c1 = coefS[j + 1], c2 = coefS[j + 2], c3 = coefS[j + 3];
        float h0 = H[s0 * 32 + f];
        float h1 = H[s1 * 32 + f];
        float h2 = H[s2 * 32 + f];
        float h3 = H[s3 * 32 + f];
        acc0 += h0 * c0; acc1 += h1 * c1; acc2 += h2 * c2; acc3 += h3 * c3;
    }
    for (; j < end; ++j) acc0 += H[srcS[j] * 32 + f] * coefS[j];
    float acc = (acc0 + acc1) + (acc2 + acc3);
    float di = dinv[node];
    float v = acc + H[node * 32 + f] * di * di;
    if constexpr (BIAS) v += b[f];
    if constexpr (RELU) v = fmaxf(v, 0.0f);
    out[node * 32 + f] = v;
    if (out2) out2[node * 32 + f] = v;
}

// ---------------- launch ----------------

extern "C" void kernel_launch(void* const* d_in, const int* in_sizes, int n_in,
                              void* d_out, int out_size, void* d_ws, size_t ws_size,
                              hipStream_t stream) {
    const float* x  = (const float*)d_in[0];
    const int*   ei = (const int*)d_in[1];
    const float* w  = (const float*)d_in[2];
    const float* W1 = (const float*)d_in[3];
    const float* b1 = (const float*)d_in[4];
    const float* W2 = (const float*)d_in[5];
    const float* b2 = (const float*)d_in[6];
    const float* W3 = (const float*)d_in[7];
    const float* b3 = (const float*)d_in[8];
    const float* W4 = (const float*)d_in[9];
    const float* b4 = (const float*)d_in[10];

    const int* src = ei;            // edge_index[0]
    const int* dst = ei + EE;       // edge_index[1]

    const int N = NN, E = EE;
    const int NB = (N + 255) / 256;

    // workspace layout (4-byte words), total 81.0 MB
    float* ws     = (float*)d_ws;
    float* dinv_w = ws;                       // N (pad 50176)
    float* dinv_1 = ws + 50176;               // N
    int*   counts = (int*)(ws + 100352);      // N
    int*   row_off= (int*)(ws + 150528);      // N+1
    int*   pos    = (int*)(ws + 200704);      // N
    int*   bsum   = (int*)(ws + 250880);      // 256
    int*   srcS   = (int*)(ws + 251136);      // E
    float* coefwS = ws + 1051136;             // E
    float* coef1S = ws + 1851136;             // E
    float* g1     = ws + 2651136;             // N*64
    float* h1     = ws + 5851136;             // N*64
    float* g2     = ws + 9051136;             // N*32
    float* zws    = ws + 10651136;            // N*32
    float* p3     = ws + 12251136;            // N*32
    float* dbuf   = ws + 13851136;            // N*64
    float* p4     = ws + 17051136;            // N*64  (end 20,251,136 words)

    float* recon = (float*)d_out;             // N*256
    float* zout  = (float*)d_out + NN * 256;  // N*32

    // ---- normalization + CSR build ----
    hipMemsetAsync(dinv_w, 0, N * sizeof(float), stream);
    hipMemsetAsync(counts, 0, N * sizeof(int), stream);
    deg_kernel<<<(E + 255) / 256, 256, 0, stream>>>(dst, w, dinv_w, counts, E);
    dinv_kernel<<<NB, 256, 0, stream>>>(dinv_w, dinv_1, counts, N);
    scan_block_kernel<<<NB, 256, 0, stream>>>(counts, row_off, bsum, N);
    scan_bsum_kernel<<<1, 256, 0, stream>>>(bsum, NB);
    scan_add_kernel<<<NB, 256, 0, stream>>>(row_off, bsum, pos, N, E);
    fill_kernel<<<(E + 255) / 256, 256, 0, stream>>>(src, dst, w, dinv_w, dinv_1,
                                                     pos, srcS, coefwS, coef1S, E);

    // ---- layer 1: h1 = relu(prop_w(x@W1) + b1) ----
    tgemm_kernel<256, 64, false, false><<<dim3((N + 63) / 64, 1), 256, 0, stream>>>(x, W1, nullptr, g1, N);
    pull64_kernel<true, true><<<(N + 3) / 4, 256, 0, stream>>>(row_off, srcS, coefwS, g1, dinv_w, b1, h1, N);

    // ---- layer 2: z = relu(prop_w(h1@W2) + b2) -> zws (+ copy to zout) ----
    gemm_kernel<64, 32, false, false><<<(N + 127) / 128, 256, 0, stream>>>(h1, W2, nullptr, g2, N);
    pull32_kernel<true, true><<<(N + 7) / 8, 256, 0, stream>>>(row_off, srcS, coefwS, g2, dinv_w, b2, zws, zout, N);

    // ---- layer 3: d = relu(prop_w(z) @ W3 + b3)   (propagate in 32-dim space) ----
    pull32_kernel<false, false><<<(N + 7) / 8, 256, 0, stream>>>(row_off, srcS, coefwS, zws, dinv_w, nullptr, p3, nullptr, N);
    gemm_kernel<32, 64, true, true><<<(N + 63) / 64, 256, 0, stream>>>(p3, W3, b3, dbuf, N);

    // ---- layer 4: recon = prop_1(d) @ W4 + b4     (propagate in 64-dim space) ----
    pull64_kernel<false, false><<<(N + 3) / 4, 256, 0, stream>>>(row_off, srcS, coef1S, dbuf, dinv_1, nullptr, p4, N);
    tgemm_kernel<64, 256, true, false><<<dim3((N + 63) / 64, 4), 256, 0, stream>>>(p4, W4, b4, recon, N);

    (void)in_sizes; (void)n_in; (void)out_size; (void)ws_size;
}

// Round 7
// 329.000 us; speedup vs baseline: 10.3845x; 1.0573x over previous
//
#include <hip/hip_runtime.h>

#define NN 50000
#define EE 800000
#define NP 50176   // padded N stride for shard arrays

// ---------------- sharded count histogram (low-contention) ----------------
__global__ void cnt8_kernel(const int* __restrict__ dst, int* __restrict__ cnt8, int E) {
    int e = blockIdx.x * 256 + threadIdx.x;
    if (e < E) {
        int sh = (e >> 8) & 7;
        atomicAdd(&cnt8[sh * NP + dst[e]], 1);
    }
}

__global__ void reduce_cnt_kernel(const int* __restrict__ cnt8, int* __restrict__ counts,
                                  float* __restrict__ dinv_1, int N) {
    int n = blockIdx.x * 256 + threadIdx.x;
    if (n < N) {
        int c = 0;
#pragma unroll
        for (int s = 0; s < 8; ++s) c += cnt8[s * NP + n];
        counts[n] = c;
        dinv_1[n] = rsqrtf((float)c + 1.0f);
    }
}

// ---------------- exclusive scan of counts -> row_off ----------------
__global__ void scan_block_kernel(const int* __restrict__ counts, int* __restrict__ row_off,
                                  int* __restrict__ bsum, int N) {
    __shared__ int tmp[256];
    int i = blockIdx.x * 256 + threadIdx.x;
    int v = (i < N) ? counts[i] : 0;
    tmp[threadIdx.x] = v;
    __syncthreads();
    for (int off = 1; off < 256; off <<= 1) {
        int t = (threadIdx.x >= off) ? tmp[threadIdx.x - off] : 0;
        __syncthreads();
        tmp[threadIdx.x] += t;
        __syncthreads();
    }
    if (i < N) row_off[i] = tmp[threadIdx.x] - v;   // exclusive within block
    if (threadIdx.x == 255) bsum[blockIdx.x] = tmp[255];
}

__global__ void scan_bsum_kernel(int* __restrict__ bsum, int nb) {
    __shared__ int tmp[256];
    int v = (threadIdx.x < nb) ? bsum[threadIdx.x] : 0;
    tmp[threadIdx.x] = v;
    __syncthreads();
    for (int off = 1; off < 256; off <<= 1) {
        int t = (threadIdx.x >= off) ? tmp[threadIdx.x - off] : 0;
        __syncthreads();
        tmp[threadIdx.x] += t;
        __syncthreads();
    }
    if (threadIdx.x < nb) bsum[threadIdx.x] = tmp[threadIdx.x] - v;  // exclusive
}

__global__ void scan_add_kernel(int* __restrict__ row_off, const int* __restrict__ bsum,
                                int N, int E) {
    int i = blockIdx.x * 256 + threadIdx.x;
    if (i < N) row_off[i] += bsum[i >> 8];
    if (i == 0) row_off[N] = E;
}

// ---------------- per-(shard,node) cursors ----------------
__global__ void off8_kernel(const int* __restrict__ row_off, const int* __restrict__ cnt8,
                            int* __restrict__ pos8, int N) {
    int n = blockIdx.x * 256 + threadIdx.x;
    if (n < N) {
        int r = row_off[n];
#pragma unroll
        for (int s = 0; s < 8; ++s) { pos8[s * NP + n] = r; r += cnt8[s * NP + n]; }
    }
}

// ---------------- CSR fill (sharded cursor, raw w) ----------------
__global__ void fill8_kernel(const int* __restrict__ src, const int* __restrict__ dst,
                             const float* __restrict__ w, int* __restrict__ pos8,
                             int* __restrict__ srcS, float* __restrict__ wS, int E) {
    int e = blockIdx.x * 256 + threadIdx.x;
    if (e < E) {
        int sh = (e >> 8) & 7;
        int p = atomicAdd(&pos8[sh * NP + dst[e]], 1);
        srcS[p] = src[e];
        wS[p] = w[e];
    }
}

// ---------------- weighted degree via segmented sum (no atomics) ----------------
__global__ void degw_kernel(const int* __restrict__ row_off, const float* __restrict__ wS,
                            float* __restrict__ dinv_w, int N) {
    int n = blockIdx.x * 256 + threadIdx.x;
    if (n < N) {
        int beg = row_off[n], end = row_off[n + 1];
        float a0 = 0.f, a1 = 0.f, a2 = 0.f, a3 = 0.f;
        int j = beg, end4 = beg + ((end - beg) & ~3);
        for (; j < end4; j += 4) { a0 += wS[j]; a1 += wS[j+1]; a2 += wS[j+2]; a3 += wS[j+3]; }
        for (; j < end; ++j) a0 += wS[j];
        dinv_w[n] = rsqrtf((a0 + a1) + (a2 + a3) + 1.0f);
    }
}

// ---------------- coefficients per CSR row ----------------
__global__ void coef8_kernel(const int* __restrict__ row_off, const int* __restrict__ srcS,
                             const float* __restrict__ wS,
                             const float* __restrict__ dinv_w, const float* __restrict__ dinv_1,
                             float* __restrict__ coefwS, float* __restrict__ coef1S, int N) {
    int n = blockIdx.x * 16 + (threadIdx.x >> 4);   // 16 nodes/block, 16 lanes/node
    int l = threadIdx.x & 15;
    if (n >= N) return;
    int beg = row_off[n], end = row_off[n + 1];
    float dw = dinv_w[n], d1 = dinv_1[n];
    for (int j = beg + l; j < end; j += 16) {
        int s = srcS[j];
        coefwS[j] = dinv_w[s] * wS[j] * dw;
        coef1S[j] = dinv_1[s] * d1;
    }
}

// ---------------- LDS-tiled GEMM: H = X @ W (+bias)(+relu) ----------------
template<int K, int DOUT, bool BIAS, bool RELU_OUT>
__global__ __launch_bounds__(256) void tgemm_kernel(const float* __restrict__ X,
                                                    const float* __restrict__ W,
                                                    const float* __restrict__ b,
                                                    float* __restrict__ H, int N) {
    constexpr int BK = 16;
    __shared__ float Xs[BK][68];
    __shared__ float Ws[BK][68];

    const int t = threadIdx.x;
    const int tx = t & 15;
    const int ty = t >> 4;
    const int brow = blockIdx.x * 64;
    const int bcol = blockIdx.y * 64;

    const int row_l = t >> 2;
    const int kq    = t & 3;
    int srow = brow + row_l;
    if (srow > N - 1) srow = N - 1;

    float acc[4][4] = {};

    for (int kc = 0; kc < K; kc += BK) {
        float4 xv = *reinterpret_cast<const float4*>(&X[srow * K + kc + kq * 4]);
        Xs[kq * 4 + 0][row_l] = xv.x;
        Xs[kq * 4 + 1][row_l] = xv.y;
        Xs[kq * 4 + 2][row_l] = xv.z;
        Xs[kq * 4 + 3][row_l] = xv.w;
        float4 wv = *reinterpret_cast<const float4*>(&W[(kc + ty) * DOUT + bcol + tx * 4]);
        *reinterpret_cast<float4*>(&Ws[ty][tx * 4]) = wv;
        __syncthreads();

#pragma unroll
        for (int kk = 0; kk < BK; ++kk) {
            float4 a = *reinterpret_cast<const float4*>(&Xs[kk][ty * 4]);
            float4 wr = *reinterpret_cast<const float4*>(&Ws[kk][tx * 4]);
            acc[0][0] += a.x * wr.x; acc[0][1] += a.x * wr.y; acc[0][2] += a.x * wr.z; acc[0][3] += a.x * wr.w;
            acc[1][0] += a.y * wr.x; acc[1][1] += a.y * wr.y; acc[1][2] += a.y * wr.z; acc[1][3] += a.y * wr.w;
            acc[2][0] += a.z * wr.x; acc[2][1] += a.z * wr.y; acc[2][2] += a.z * wr.z; acc[2][3] += a.z * wr.w;
            acc[3][0] += a.w * wr.x; acc[3][1] += a.w * wr.y; acc[3][2] += a.w * wr.z; acc[3][3] += a.w * wr.w;
        }
        __syncthreads();
    }

    float4 bv = make_float4(0.f, 0.f, 0.f, 0.f);
    if constexpr (BIAS) bv = *reinterpret_cast<const float4*>(&b[bcol + tx * 4]);
#pragma unroll
    for (int r = 0; r < 4; ++r) {
        int row = brow + ty * 4 + r;
        if (row < N) {
            float4 o = make_float4(acc[r][0] + bv.x, acc[r][1] + bv.y,
                                   acc[r][2] + bv.z, acc[r][3] + bv.w);
            if constexpr (RELU_OUT) {
                o.x = fmaxf(o.x, 0.f); o.y = fmaxf(o.y, 0.f);
                o.z = fmaxf(o.z, 0.f); o.w = fmaxf(o.w, 0.f);
            }
            *reinterpret_cast<float4*>(&H[row * DOUT + bcol + tx * 4]) = o;
        }
    }
}

// ---------------- simple register GEMM (small layers 2/3) ----------------
template<int K, int DOUT, bool BIAS, bool RELU_OUT>
__global__ void gemm_kernel(const float* __restrict__ X, const float* __restrict__ W,
                            const float* __restrict__ b, float* __restrict__ H, int N) {
    constexpr int CG = DOUT / 4;
    constexpr int RPB = (256 / CG) * 4;
    int tx = threadIdx.x % CG;
    int ty = threadIdx.x / CG;
    int row0 = blockIdx.x * RPB + ty * 4;
    int col0 = tx * 4;

    float acc[4][4] = {};
    for (int k = 0; k < K; k += 4) {
        float4 w0 = *reinterpret_cast<const float4*>(&W[(k + 0) * DOUT + col0]);
        float4 w1 = *reinterpret_cast<const float4*>(&W[(k + 1) * DOUT + col0]);
        float4 w2 = *reinterpret_cast<const float4*>(&W[(k + 2) * DOUT + col0]);
        float4 w3 = *reinterpret_cast<const float4*>(&W[(k + 3) * DOUT + col0]);
#pragma unroll
        for (int r = 0; r < 4; ++r) {
            int row = row0 + r;
            if (row < N) {
                float4 x4 = *reinterpret_cast<const float4*>(&X[row * K + k]);
                acc[r][0] += x4.x * w0.x + x4.y * w1.x + x4.z * w2.x + x4.w * w3.x;
                acc[r][1] += x4.x * w0.y + x4.y * w1.y + x4.z * w2.y + x4.w * w3.y;
                acc[r][2] += x4.x * w0.z + x4.y * w1.z + x4.z * w2.z + x4.w * w3.z;
                acc[r][3] += x4.x * w0.w + x4.y * w1.w + x4.z * w2.w + x4.w * w3.w;
            }
        }
    }
    float4 bv = make_float4(0.f, 0.f, 0.f, 0.f);
    if constexpr (BIAS) bv = *reinterpret_cast<const float4*>(&b[col0]);
#pragma unroll
    for (int r = 0; r < 4; ++r) {
        int row = row0 + r;
        if (row < N) {
            float4 o = make_float4(acc[r][0] + bv.x, acc[r][1] + bv.y,
                                   acc[r][2] + bv.z, acc[r][3] + bv.w);
            if constexpr (RELU_OUT) {
                o.x = fmaxf(o.x, 0.f); o.y = fmaxf(o.y, 0.f);
                o.z = fmaxf(o.z, 0.f); o.w = fmaxf(o.w, 0.f);
            }
            *reinterpret_cast<float4*>(&H[row * DOUT + col0]) = o;
        }
    }
}

// ---------------- pull aggregation (zero atomics, 4-wide unrolled gathers) ----------------
template<bool BIAS, bool RELU>
__global__ void pull64_kernel(const int* __restrict__ row_off, const int* __restrict__ srcS,
                              const float* __restrict__ coefS, const float* __restrict__ H,
                              const float* __restrict__ dinv, const float* __restrict__ b,
                              float* __restrict__ out, int N) {
    int node = blockIdx.x * 4 + (threadIdx.x >> 6);
    int f = threadIdx.x & 63;
    if (node >= N) return;
    int beg = row_off[node], end = row_off[node + 1];
    float acc0 = 0.0f, acc1 = 0.0f, acc2 = 0.0f, acc3 = 0.0f;
    int j = beg;
    int end4 = beg + ((end - beg) & ~3);
    for (; j < end4; j += 4) {
        int s0 = srcS[j + 0], s1 = srcS[j + 1], s2 = srcS[j + 2], s3 = srcS[j + 3];
        float c0 = coefS[j + 0], c1 = coefS[j + 1], c2 = coefS[j + 2], c3 = coefS[j + 3];
        float h0 = H[s0 * 64 + f];
        float h1 = H[s1 * 64 + f];
        float h2 = H[s2 * 64 + f];
        float h3 = H[s3 * 64 + f];
        acc0 += h0 * c0; acc1 += h1 * c1; acc2 += h2 * c2; acc3 += h3 * c3;
    }
    for (; j < end; ++j) acc0 += H[srcS[j] * 64 + f] * coefS[j];
    float acc = (acc0 + acc1) + (acc2 + acc3);
    float di = dinv[node];
    float v = acc + H[node * 64 + f] * di * di;
    if constexpr (BIAS) v += b[f];
    if constexpr (RELU) v = fmaxf(v, 0.0f);
    out[node * 64 + f] = v;
}

template<bool BIAS, bool RELU>
__global__ void pull32_kernel(const int* __restrict__ row_off, const int* __restrict__ srcS,
                              const float* __restrict__ coefS, const float* __restrict__ H,
                              const float* __restrict__ dinv, const float* __restrict__ b,
                              float* __restrict__ out, float* __restrict__ out2, int N) {
    int node = blockIdx.x * 8 + (threadIdx.x >> 5);
    int f = threadIdx.x & 31;
    if (node >= N) return;
    int beg = row_off[node], end = row_off[node + 1];
    float acc0 = 0.0f, acc1 = 0.0f, acc2 = 0.0f, acc3 = 0.0f;
    int j = beg;
    int end4 = beg + ((end - beg) & ~3);
    for (; j < end4; j += 4) {
        int s0 = srcS[j + 0], s1 = srcS[j + 1], s2 = srcS[j + 2], s3 = srcS[j + 3];
        float c0 = coefS[j + 0], c1 = coefS[j + 1], c2 = coefS[j + 2], c3 = coefS[j + 3];
        float h0 = H[s0 * 32 + f];
        float h1 = H[s1 * 32 + f];
        float h2 = H[s2 * 32 + f];
        float h3 = H[s3 * 32 + f];
        acc0 += h0 * c0; acc1 += h1 * c1; acc2 += h2 * c2; acc3 += h3 * c3;
    }
    for (; j < end; ++j) acc0 += H[srcS[j] * 32 + f] * coefS[j];
    float acc = (acc0 + acc1) + (acc2 + acc3);
    float di = dinv[node];
    float v = acc + H[node * 32 + f] * di * di;
    if constexpr (BIAS) v += b[f];
    if constexpr (RELU) v = fmaxf(v, 0.0f);
    out[node * 32 + f] = v;
    if (out2) out2[node * 32 + f] = v;
}

// ---------------- launch ----------------

extern "C" void kernel_launch(void* const* d_in, const int* in_sizes, int n_in,
                              void* d_out, int out_size, void* d_ws, size_t ws_size,
                              hipStream_t stream) {
    const float* x  = (const float*)d_in[0];
    const int*   ei = (const int*)d_in[1];
    const float* w  = (const float*)d_in[2];
    const float* W1 = (const float*)d_in[3];
    const float* b1 = (const float*)d_in[4];
    const float* W2 = (const float*)d_in[5];
    const float* b2 = (const float*)d_in[6];
    const float* W3 = (const float*)d_in[7];
    const float* b3 = (const float*)d_in[8];
    const float* W4 = (const float*)d_in[9];
    const float* b4 = (const float*)d_in[10];

    const int* src = ei;            // edge_index[0]
    const int* dst = ei + EE;       // edge_index[1]

    const int N = NN, E = EE;
    const int NB = (N + 255) / 256;

    // workspace layout (4-byte words), total 74.4 MB
    float* ws     = (float*)d_ws;
    float* dinv_w = ws;                       // NP
    float* dinv_1 = ws + 50176;               // NP
    int*   counts = (int*)(ws + 100352);      // NP
    int*   row_off= (int*)(ws + 150528);      // N+1 (pad NP)
    int*   bsum   = (int*)(ws + 200704);      // 256
    int*   cnt8   = (int*)(ws + 200960);      // 8*NP
    int*   pos8   = (int*)(ws + 602368);      // 8*NP
    int*   srcS   = (int*)(ws + 1003776);     // E
    float* wS     = ws + 1803776;             // E
    float* coefwS = ws + 2603776;             // E
    float* coef1S = ws + 3403776;             // E
    float* g1     = ws + 4203776;             // N*64 (aliased by dbuf later)
    float* h1     = ws + 7403776;             // N*64
    float* g2     = ws + 10603776;            // N*32
    float* zws    = ws + 12203776;            // N*32
    float* p3     = ws + 13803776;            // N*32
    float* p4     = ws + 15403776;            // N*64  (end 18,603,776 words)
    float* dbuf   = g1;                       // g1 dead after L1 pull

    float* recon = (float*)d_out;             // N*256
    float* zout  = (float*)d_out + NN * 256;  // N*32

    // ---- CSR build + normalization (sharded, low-contention) ----
    hipMemsetAsync(cnt8, 0, 8 * NP * sizeof(int), stream);
    cnt8_kernel<<<(E + 255) / 256, 256, 0, stream>>>(dst, cnt8, E);
    reduce_cnt_kernel<<<NB, 256, 0, stream>>>(cnt8, counts, dinv_1, N);
    scan_block_kernel<<<NB, 256, 0, stream>>>(counts, row_off, bsum, N);
    scan_bsum_kernel<<<1, 256, 0, stream>>>(bsum, NB);
    scan_add_kernel<<<NB, 256, 0, stream>>>(row_off, bsum, N, E);
    off8_kernel<<<NB, 256, 0, stream>>>(row_off, cnt8, pos8, N);
    fill8_kernel<<<(E + 255) / 256, 256, 0, stream>>>(src, dst, w, pos8, srcS, wS, E);
    degw_kernel<<<NB, 256, 0, stream>>>(row_off, wS, dinv_w, N);
    coef8_kernel<<<(N + 15) / 16, 256, 0, stream>>>(row_off, srcS, wS, dinv_w, dinv_1,
                                                    coefwS, coef1S, N);

    // ---- layer 1: h1 = relu(prop_w(x@W1) + b1) ----
    tgemm_kernel<256, 64, false, false><<<dim3((N + 63) / 64, 1), 256, 0, stream>>>(x, W1, nullptr, g1, N);
    pull64_kernel<true, true><<<(N + 3) / 4, 256, 0, stream>>>(row_off, srcS, coefwS, g1, dinv_w, b1, h1, N);

    // ---- layer 2: z = relu(prop_w(h1@W2) + b2) -> zws (+ copy to zout) ----
    gemm_kernel<64, 32, false, false><<<(N + 127) / 128, 256, 0, stream>>>(h1, W2, nullptr, g2, N);
    pull32_kernel<true, true><<<(N + 7) / 8, 256, 0, stream>>>(row_off, srcS, coefwS, g2, dinv_w, b2, zws, zout, N);

    // ---- layer 3: d = relu(prop_w(z) @ W3 + b3)   (propagate in 32-dim space) ----
    pull32_kernel<false, false><<<(N + 7) / 8, 256, 0, stream>>>(row_off, srcS, coefwS, zws, dinv_w, nullptr, p3, nullptr, N);
    gemm_kernel<32, 64, true, true><<<(N + 63) / 64, 256, 0, stream>>>(p3, W3, b3, dbuf, N);

    // ---- layer 4: recon = prop_1(d) @ W4 + b4     (propagate in 64-dim space) ----
    pull64_kernel<false, false><<<(N + 3) / 4, 256, 0, stream>>>(row_off, srcS, coef1S, dbuf, dinv_1, nullptr, p4, N);
    tgemm_kernel<64, 256, true, false><<<dim3((N + 63) / 64, 4), 256, 0, stream>>>(p4, W4, b4, recon, N);

    (void)in_sizes; (void)n_in; (void)out_size; (void)ws_size;
}

// Round 8
// 312.982 us; speedup vs baseline: 10.9159x; 1.0512x over previous
//
#include <hip/hip_runtime.h>

#define NN 50000
#define EE 800000
#define NP 50176   // padded N stride for shard arrays

// ---------------- sharded count histogram (low-contention) ----------------
__global__ void cnt8_kernel(const int* __restrict__ dst, int* __restrict__ cnt8, int E) {
    int e = blockIdx.x * 256 + threadIdx.x;
    if (e < E) {
        int sh = (e >> 8) & 7;
        atomicAdd(&cnt8[sh * NP + dst[e]], 1);
    }
}

__global__ void reduce_cnt_kernel(const int* __restrict__ cnt8, int* __restrict__ counts,
                                  float* __restrict__ dinv_1, int N) {
    int n = blockIdx.x * 256 + threadIdx.x;
    if (n < N) {
        int c = 0;
#pragma unroll
        for (int s = 0; s < 8; ++s) c += cnt8[s * NP + n];
        counts[n] = c;
        dinv_1[n] = rsqrtf((float)c + 1.0f);
    }
}

// ---------------- exclusive scan of counts -> row_off ----------------
__global__ void scan_block_kernel(const int* __restrict__ counts, int* __restrict__ row_off,
                                  int* __restrict__ bsum, int N) {
    __shared__ int tmp[256];
    int i = blockIdx.x * 256 + threadIdx.x;
    int v = (i < N) ? counts[i] : 0;
    tmp[threadIdx.x] = v;
    __syncthreads();
    for (int off = 1; off < 256; off <<= 1) {
        int t = (threadIdx.x >= off) ? tmp[threadIdx.x - off] : 0;
        __syncthreads();
        tmp[threadIdx.x] += t;
        __syncthreads();
    }
    if (i < N) row_off[i] = tmp[threadIdx.x] - v;   // exclusive within block
    if (threadIdx.x == 255) bsum[blockIdx.x] = tmp[255];
}

__global__ void scan_bsum_kernel(int* __restrict__ bsum, int nb) {
    __shared__ int tmp[256];
    int v = (threadIdx.x < nb) ? bsum[threadIdx.x] : 0;
    tmp[threadIdx.x] = v;
    __syncthreads();
    for (int off = 1; off < 256; off <<= 1) {
        int t = (threadIdx.x >= off) ? tmp[threadIdx.x - off] : 0;
        __syncthreads();
        tmp[threadIdx.x] += t;
        __syncthreads();
    }
    if (threadIdx.x < nb) bsum[threadIdx.x] = tmp[threadIdx.x] - v;  // exclusive
}

__global__ void scan_add_kernel(int* __restrict__ row_off, const int* __restrict__ bsum,
                                int N, int E) {
    int i = blockIdx.x * 256 + threadIdx.x;
    if (i < N) row_off[i] += bsum[i >> 8];
    if (i == 0) row_off[N] = E;
}

// ---------------- per-(shard,node) cursors ----------------
__global__ void off8_kernel(const int* __restrict__ row_off, const int* __restrict__ cnt8,
                            int* __restrict__ pos8, int N) {
    int n = blockIdx.x * 256 + threadIdx.x;
    if (n < N) {
        int r = row_off[n];
#pragma unroll
        for (int s = 0; s < 8; ++s) { pos8[s * NP + n] = r; r += cnt8[s * NP + n]; }
    }
}

// ---------------- CSR fill (sharded cursor, packed 8B store) ----------------
__global__ void fill8_kernel(const int* __restrict__ src, const int* __restrict__ dst,
                             const float* __restrict__ w, int* __restrict__ pos8,
                             int2* __restrict__ ewS, int E) {
    int e = blockIdx.x * 256 + threadIdx.x;
    if (e < E) {
        int sh = (e >> 8) & 7;
        int p = atomicAdd(&pos8[sh * NP + dst[e]], 1);
        ewS[p] = make_int2(src[e], __float_as_int(w[e]));
    }
}

// ---------------- weighted degree via segmented sum (no atomics) ----------------
__global__ void degw_kernel(const int* __restrict__ row_off, const int2* __restrict__ ewS,
                            float* __restrict__ dinv_w, int N) {
    int n = blockIdx.x * 256 + threadIdx.x;
    if (n < N) {
        int beg = row_off[n], end = row_off[n + 1];
        float a0 = 0.f, a1 = 0.f, a2 = 0.f, a3 = 0.f;
        int j = beg, end4 = beg + ((end - beg) & ~3);
        for (; j < end4; j += 4) {
            a0 += __int_as_float(ewS[j + 0].y);
            a1 += __int_as_float(ewS[j + 1].y);
            a2 += __int_as_float(ewS[j + 2].y);
            a3 += __int_as_float(ewS[j + 3].y);
        }
        for (; j < end; ++j) a0 += __int_as_float(ewS[j].y);
        dinv_w[n] = rsqrtf((a0 + a1) + (a2 + a3) + 1.0f);
    }
}

// ---------------- coefficients + srcS unpack per CSR row (coalesced writes) ----------------
__global__ void coef8_kernel(const int* __restrict__ row_off, const int2* __restrict__ ewS,
                             const float* __restrict__ dinv_w, const float* __restrict__ dinv_1,
                             int* __restrict__ srcS,
                             float* __restrict__ coefwS, float* __restrict__ coef1S, int N) {
    int n = blockIdx.x * 16 + (threadIdx.x >> 4);   // 16 nodes/block, 16 lanes/node
    int l = threadIdx.x & 15;
    if (n >= N) return;
    int beg = row_off[n], end = row_off[n + 1];
    float dw = dinv_w[n], d1 = dinv_1[n];
    for (int j = beg + l; j < end; j += 16) {
        int2 ew = ewS[j];
        int s = ew.x;
        srcS[j] = s;
        coefwS[j] = dinv_w[s] * __int_as_float(ew.y) * dw;
        coef1S[j] = dinv_1[s] * d1;
    }
}

// ---------------- LDS-tiled GEMM: H = X @ W (+bias)(+relu) ----------------
template<int K, int DOUT, bool BIAS, bool RELU_OUT>
__global__ __launch_bounds__(256) void tgemm_kernel(const float* __restrict__ X,
                                                    const float* __restrict__ W,
                                                    const float* __restrict__ b,
                                                    float* __restrict__ H, int N) {
    constexpr int BK = 16;
    __shared__ float Xs[BK][68];
    __shared__ float Ws[BK][68];

    const int t = threadIdx.x;
    const int tx = t & 15;
    const int ty = t >> 4;
    const int brow = blockIdx.x * 64;
    const int bcol = blockIdx.y * 64;

    const int row_l = t >> 2;
    const int kq    = t & 3;
    int srow = brow + row_l;
    if (srow > N - 1) srow = N - 1;

    float acc[4][4] = {};

    for (int kc = 0; kc < K; kc += BK) {
        float4 xv = *reinterpret_cast<const float4*>(&X[srow * K + kc + kq * 4]);
        Xs[kq * 4 + 0][row_l] = xv.x;
        Xs[kq * 4 + 1][row_l] = xv.y;
        Xs[kq * 4 + 2][row_l] = xv.z;
        Xs[kq * 4 + 3][row_l] = xv.w;
        float4 wv = *reinterpret_cast<const float4*>(&W[(kc + ty) * DOUT + bcol + tx * 4]);
        *reinterpret_cast<float4*>(&Ws[ty][tx * 4]) = wv;
        __syncthreads();

#pragma unroll
        for (int kk = 0; kk < BK; ++kk) {
            float4 a = *reinterpret_cast<const float4*>(&Xs[kk][ty * 4]);
            float4 wr = *reinterpret_cast<const float4*>(&Ws[kk][tx * 4]);
            acc[0][0] += a.x * wr.x; acc[0][1] += a.x * wr.y; acc[0][2] += a.x * wr.z; acc[0][3] += a.x * wr.w;
            acc[1][0] += a.y * wr.x; acc[1][1] += a.y * wr.y; acc[1][2] += a.y * wr.z; acc[1][3] += a.y * wr.w;
            acc[2][0] += a.z * wr.x; acc[2][1] += a.z * wr.y; acc[2][2] += a.z * wr.z; acc[2][3] += a.z * wr.w;
            acc[3][0] += a.w * wr.x; acc[3][1] += a.w * wr.y; acc[3][2] += a.w * wr.z; acc[3][3] += a.w * wr.w;
        }
        __syncthreads();
    }

    float4 bv = make_float4(0.f, 0.f, 0.f, 0.f);
    if constexpr (BIAS) bv = *reinterpret_cast<const float4*>(&b[bcol + tx * 4]);
#pragma unroll
    for (int r = 0; r < 4; ++r) {
        int row = brow + ty * 4 + r;
        if (row < N) {
            float4 o = make_float4(acc[r][0] + bv.x, acc[r][1] + bv.y,
                                   acc[r][2] + bv.z, acc[r][3] + bv.w);
            if constexpr (RELU_OUT) {
                o.x = fmaxf(o.x, 0.f); o.y = fmaxf(o.y, 0.f);
                o.z = fmaxf(o.z, 0.f); o.w = fmaxf(o.w, 0.f);
            }
            *reinterpret_cast<float4*>(&H[row * DOUT + bcol + tx * 4]) = o;
        }
    }
}

// ---------------- simple register GEMM (small layers 2/3) ----------------
template<int K, int DOUT, bool BIAS, bool RELU_OUT>
__global__ void gemm_kernel(const float* __restrict__ X, const float* __restrict__ W,
                            const float* __restrict__ b, float* __restrict__ H, int N) {
    constexpr int CG = DOUT / 4;
    constexpr int RPB = (256 / CG) * 4;
    int tx = threadIdx.x % CG;
    int ty = threadIdx.x / CG;
    int row0 = blockIdx.x * RPB + ty * 4;
    int col0 = tx * 4;

    float acc[4][4] = {};
    for (int k = 0; k < K; k += 4) {
        float4 w0 = *reinterpret_cast<const float4*>(&W[(k + 0) * DOUT + col0]);
        float4 w1 = *reinterpret_cast<const float4*>(&W[(k + 1) * DOUT + col0]);
        float4 w2 = *reinterpret_cast<const float4*>(&W[(k + 2) * DOUT + col0]);
        float4 w3 = *reinterpret_cast<const float4*>(&W[(k + 3) * DOUT + col0]);
#pragma unroll
        for (int r = 0; r < 4; ++r) {
            int row = row0 + r;
            if (row < N) {
                float4 x4 = *reinterpret_cast<const float4*>(&X[row * K + k]);
                acc[r][0] += x4.x * w0.x + x4.y * w1.x + x4.z * w2.x + x4.w * w3.x;
                acc[r][1] += x4.x * w0.y + x4.y * w1.y + x4.z * w2.y + x4.w * w3.y;
                acc[r][2] += x4.x * w0.z + x4.y * w1.z + x4.z * w2.z + x4.w * w3.z;
                acc[r][3] += x4.x * w0.w + x4.y * w1.w + x4.z * w2.w + x4.w * w3.w;
            }
        }
    }
    float4 bv = make_float4(0.f, 0.f, 0.f, 0.f);
    if constexpr (BIAS) bv = *reinterpret_cast<const float4*>(&b[col0]);
#pragma unroll
    for (int r = 0; r < 4; ++r) {
        int row = row0 + r;
        if (row < N) {
            float4 o = make_float4(acc[r][0] + bv.x, acc[r][1] + bv.y,
                                   acc[r][2] + bv.z, acc[r][3] + bv.w);
            if constexpr (RELU_OUT) {
                o.x = fmaxf(o.x, 0.f); o.y = fmaxf(o.y, 0.f);
                o.z = fmaxf(o.z, 0.f); o.w = fmaxf(o.w, 0.f);
            }
            *reinterpret_cast<float4*>(&H[row * DOUT + col0]) = o;
        }
    }
}

// ---------------- pull aggregation (zero atomics, 8-wide unrolled gathers) ----------------
template<bool BIAS, bool RELU>
__global__ void pull64_kernel(const int* __restrict__ row_off, const int* __restrict__ srcS,
                              const float* __restrict__ coefS, const float* __restrict__ H,
                              const float* __restrict__ dinv, const float* __restrict__ b,
                              float* __restrict__ out, int N) {
    int node = blockIdx.x * 4 + (threadIdx.x >> 6);
    int f = threadIdx.x & 63;
    if (node >= N) return;
    int beg = row_off[node], end = row_off[node + 1];
    float a0 = 0.f, a1 = 0.f, a2 = 0.f, a3 = 0.f, a4 = 0.f, a5 = 0.f, a6 = 0.f, a7 = 0.f;
    int j = beg;
    int end8 = beg + ((end - beg) & ~7);
    for (; j < end8; j += 8) {
        int s0 = srcS[j+0], s1 = srcS[j+1], s2 = srcS[j+2], s3 = srcS[j+3];
        int s4 = srcS[j+4], s5 = srcS[j+5], s6 = srcS[j+6], s7 = srcS[j+7];
        float c0 = coefS[j+0], c1 = coefS[j+1], c2 = coefS[j+2], c3 = coefS[j+3];
        float c4 = coefS[j+4], c5 = coefS[j+5], c6 = coefS[j+6], c7 = coefS[j+7];
        float h0 = H[s0 * 64 + f], h1 = H[s1 * 64 + f], h2 = H[s2 * 64 + f], h3 = H[s3 * 64 + f];
        float h4 = H[s4 * 64 + f], h5 = H[s5 * 64 + f], h6 = H[s6 * 64 + f], h7 = H[s7 * 64 + f];
        a0 += h0 * c0; a1 += h1 * c1; a2 += h2 * c2; a3 += h3 * c3;
        a4 += h4 * c4; a5 += h5 * c5; a6 += h6 * c6; a7 += h7 * c7;
    }
    int end4 = j + ((end - j) & ~3);
    for (; j < end4; j += 4) {
        int s0 = srcS[j+0], s1 = srcS[j+1], s2 = srcS[j+2], s3 = srcS[j+3];
        float c0 = coefS[j+0], c1 = coefS[j+1], c2 = coefS[j+2], c3 = coefS[j+3];
        a0 += H[s0 * 64 + f] * c0; a1 += H[s1 * 64 + f] * c1;
        a2 += H[s2 * 64 + f] * c2; a3 += H[s3 * 64 + f] * c3;
    }
    for (; j < end; ++j) a0 += H[srcS[j] * 64 + f] * coefS[j];
    float acc = ((a0 + a1) + (a2 + a3)) + ((a4 + a5) + (a6 + a7));
    float di = dinv[node];
    float v = acc + H[node * 64 + f] * di * di;
    if constexpr (BIAS) v += b[f];
    if constexpr (RELU) v = fmaxf(v, 0.0f);
    out[node * 64 + f] = v;
}

template<bool BIAS, bool RELU>
__global__ void pull32_kernel(const int* __restrict__ row_off, const int* __restrict__ srcS,
                              const float* __restrict__ coefS, const float* __restrict__ H,
                              const float* __restrict__ dinv, const float* __restrict__ b,
                              float* __restrict__ out, float* __restrict__ out2, int N) {
    int node = blockIdx.x * 8 + (threadIdx.x >> 5);
    int f = threadIdx.x & 31;
    if (node >= N) return;
    int beg = row_off[node], end = row_off[node + 1];
    float a0 = 0.f, a1 = 0.f, a2 = 0.f, a3 = 0.f, a4 = 0.f, a5 = 0.f, a6 = 0.f, a7 = 0.f;
    int j = beg;
    int end8 = beg + ((end - beg) & ~7);
    for (; j < end8; j += 8) {
        int s0 = srcS[j+0], s1 = srcS[j+1], s2 = srcS[j+2], s3 = srcS[j+3];
        int s4 = srcS[j+4], s5 = srcS[j+5], s6 = srcS[j+6], s7 = srcS[j+7];
        float c0 = coefS[j+0], c1 = coefS[j+1], c2 = coefS[j+2], c3 = coefS[j+3];
        float c4 = coefS[j+4], c5 = coefS[j+5], c6 = coefS[j+6], c7 = coefS[j+7];
        float h0 = H[s0 * 32 + f], h1 = H[s1 * 32 + f], h2 = H[s2 * 32 + f], h3 = H[s3 * 32 + f];
        float h4 = H[s4 * 32 + f], h5 = H[s5 * 32 + f], h6 = H[s6 * 32 + f], h7 = H[s7 * 32 + f];
        a0 += h0 * c0; a1 += h1 * c1; a2 += h2 * c2; a3 += h3 * c3;
        a4 += h4 * c4; a5 += h5 * c5; a6 += h6 * c6; a7 += h7 * c7;
    }
    int end4 = j + ((end - j) & ~3);
    for (; j < end4; j += 4) {
        int s0 = srcS[j+0], s1 = srcS[j+1], s2 = srcS[j+2], s3 = srcS[j+3];
        float c0 = coefS[j+0], c1 = coefS[j+1], c2 = coefS[j+2], c3 = coefS[j+3];
        a0 += H[s0 * 32 + f] * c0; a1 += H[s1 * 32 + f] * c1;
        a2 += H[s2 * 32 + f] * c2; a3 += H[s3 * 32 + f] * c3;
    }
    for (; j < end; ++j) a0 += H[srcS[j] * 32 + f] * coefS[j];
    float acc = ((a0 + a1) + (a2 + a3)) + ((a4 + a5) + (a6 + a7));
    float di = dinv[node];
    float v = acc + H[node * 32 + f] * di * di;
    if constexpr (BIAS) v += b[f];
    if constexpr (RELU) v = fmaxf(v, 0.0f);
    out[node * 32 + f] = v;
    if (out2) out2[node * 32 + f] = v;
}

// ---------------- launch ----------------

extern "C" void kernel_launch(void* const* d_in, const int* in_sizes, int n_in,
                              void* d_out, int out_size, void* d_ws, size_t ws_size,
                              hipStream_t stream) {
    const float* x  = (const float*)d_in[0];
    const int*   ei = (const int*)d_in[1];
    const float* w  = (const float*)d_in[2];
    const float* W1 = (const float*)d_in[3];
    const float* b1 = (const float*)d_in[4];
    const float* W2 = (const float*)d_in[5];
    const float* b2 = (const float*)d_in[6];
    const float* W3 = (const float*)d_in[7];
    const float* b3 = (const float*)d_in[8];
    const float* W4 = (const float*)d_in[9];
    const float* b4 = (const float*)d_in[10];

    const int* src = ei;            // edge_index[0]
    const int* dst = ei + EE;       // edge_index[1]

    const int N = NN, E = EE;
    const int NB = (N + 255) / 256;

    // workspace layout (4-byte words), total 77.6 MB
    float* ws     = (float*)d_ws;
    float* dinv_w = ws;                       // NP
    float* dinv_1 = ws + 50176;               // NP
    int*   counts = (int*)(ws + 100352);      // NP
    int*   row_off= (int*)(ws + 150528);      // N+1 (pad NP)
    int*   bsum   = (int*)(ws + 200704);      // 256
    int*   cnt8   = (int*)(ws + 200960);      // 8*NP
    int*   pos8   = (int*)(ws + 602368);      // 8*NP
    int2*  ewS    = (int2*)(ws + 1003776);    // E int2 (2E words)
    int*   srcS   = (int*)(ws + 2603776);     // E
    float* coefwS = ws + 3403776;             // E
    float* coef1S = ws + 4203776;             // E
    float* g1     = ws + 5003776;             // N*64 (aliased by dbuf later)
    float* h1     = ws + 8203776;             // N*64
    float* g2     = ws + 11403776;            // N*32
    float* zws    = ws + 13003776;            // N*32
    float* p3     = ws + 14603776;            // N*32
    float* p4     = ws + 16203776;            // N*64  (end 19,403,776 words)
    float* dbuf   = g1;                       // g1 dead after L1 pull

    float* recon = (float*)d_out;             // N*256
    float* zout  = (float*)d_out + NN * 256;  // N*32

    // ---- CSR build + normalization (sharded, low-contention) ----
    hipMemsetAsync(cnt8, 0, 8 * NP * sizeof(int), stream);
    cnt8_kernel<<<(E + 255) / 256, 256, 0, stream>>>(dst, cnt8, E);
    reduce_cnt_kernel<<<NB, 256, 0, stream>>>(cnt8, counts, dinv_1, N);
    scan_block_kernel<<<NB, 256, 0, stream>>>(counts, row_off, bsum, N);
    scan_bsum_kernel<<<1, 256, 0, stream>>>(bsum, NB);
    scan_add_kernel<<<NB, 256, 0, stream>>>(row_off, bsum, N, E);
    off8_kernel<<<NB, 256, 0, stream>>>(row_off, cnt8, pos8, N);
    fill8_kernel<<<(E + 255) / 256, 256, 0, stream>>>(src, dst, w, pos8, ewS, E);
    degw_kernel<<<NB, 256, 0, stream>>>(row_off, ewS, dinv_w, N);
    coef8_kernel<<<(N + 15) / 16, 256, 0, stream>>>(row_off, ewS, dinv_w, dinv_1,
                                                    srcS, coefwS, coef1S, N);

    // ---- layer 1: h1 = relu(prop_w(x@W1) + b1) ----
    tgemm_kernel<256, 64, false, false><<<dim3((N + 63) / 64, 1), 256, 0, stream>>>(x, W1, nullptr, g1, N);
    pull64_kernel<true, true><<<(N + 3) / 4, 256, 0, stream>>>(row_off, srcS, coefwS, g1, dinv_w, b1, h1, N);

    // ---- layer 2: z = relu(prop_w(h1@W2) + b2) -> zws (+ copy to zout) ----
    gemm_kernel<64, 32, false, false><<<(N + 127) / 128, 256, 0, stream>>>(h1, W2, nullptr, g2, N);
    pull32_kernel<true, true><<<(N + 7) / 8, 256, 0, stream>>>(row_off, srcS, coefwS, g2, dinv_w, b2, zws, zout, N);

    // ---- layer 3: d = relu(prop_w(z) @ W3 + b3)   (propagate in 32-dim space) ----
    pull32_kernel<false, false><<<(N + 7) / 8, 256, 0, stream>>>(row_off, srcS, coefwS, zws, dinv_w, nullptr, p3, nullptr, N);
    gemm_kernel<32, 64, true, true><<<(N + 63) / 64, 256, 0, stream>>>(p3, W3, b3, dbuf, N);

    // ---- layer 4: recon = prop_1(d) @ W4 + b4     (propagate in 64-dim space) ----
    pull64_kernel<false, false><<<(N + 3) / 4, 256, 0, stream>>>(row_off, srcS, coef1S, dbuf, dinv_1, nullptr, p4, N);
    tgemm_kernel<64, 256, true, false><<<dim3((N + 63) / 64, 4), 256, 0, stream>>>(p4, W4, b4, recon, N);

    (void)in_sizes; (void)n_in; (void)out_size; (void)ws_size;
}

// Round 9
// 263.064 us; speedup vs baseline: 12.9873x; 1.1898x over previous
//
#include <hip/hip_runtime.h>

#define NN 50000
#define EE 800000
#define NP 50176        // padded N stride
#define BSH 7           // bucket shift: 128 nodes/bucket
#define NBUK 391        // ((NN-1)>>BSH)+1
#define BCAP 4096       // max edges per bucket held in LDS (mean 2046, +45 sigma)
#define NBLKA 128       // blocks for hist/partition passes

// ---------------- bucket histogram (LDS-aggregated) ----------------
__global__ __launch_bounds__(256) void histb_kernel(const int* __restrict__ dst,
                                                    int* __restrict__ bcnt, int E) {
    __shared__ int h[512];
    int t = threadIdx.x;
    h[t] = 0; h[t + 256] = 0;
    __syncthreads();
    int chunk = (E + NBLKA - 1) / NBLKA;
    int beg = blockIdx.x * chunk;
    int end = min(beg + chunk, E);
    for (int e = beg + t; e < end; e += 256) atomicAdd(&h[dst[e] >> BSH], 1);
    __syncthreads();
    if (h[t]) atomicAdd(&bcnt[t], h[t]);
    if (h[t + 256]) atomicAdd(&bcnt[t + 256], h[t + 256]);
}

// ---------------- bucket offset scan (single block, 512 threads) ----------------
__global__ __launch_bounds__(512) void bscan_kernel(const int* __restrict__ bcnt,
                                                    int* __restrict__ boff, int* __restrict__ cur,
                                                    int* __restrict__ row_off, int E, int N) {
    __shared__ int tmp[512];
    int t = threadIdx.x;
    int v = bcnt[t];
    tmp[t] = v;
    __syncthreads();
    for (int off = 1; off < 512; off <<= 1) {
        int u = (t >= off) ? tmp[t - off] : 0;
        __syncthreads();
        tmp[t] += u;
        __syncthreads();
    }
    int excl = tmp[t] - v;
    boff[t] = excl;
    cur[t] = excl;
    if (t == 511) boff[512] = tmp[511];   // == E
    if (t == 0) row_off[N] = E;
}

// ---------------- pass A: partition edges into buckets ----------------
__global__ __launch_bounds__(256) void passA_kernel(const int* __restrict__ src,
                                                    const int* __restrict__ dst,
                                                    const float* __restrict__ w,
                                                    int* __restrict__ cur,
                                                    int2* __restrict__ ebuf, int E) {
    __shared__ int h[512];
    __shared__ int bs[512];
    __shared__ int cl[512];
    int t = threadIdx.x;
    h[t] = 0; h[t + 256] = 0;
    __syncthreads();
    int chunk = (E + NBLKA - 1) / NBLKA;
    int beg = blockIdx.x * chunk;
    int end = min(beg + chunk, E);
    for (int e = beg + t; e < end; e += 256) atomicAdd(&h[dst[e] >> BSH], 1);
    __syncthreads();
#pragma unroll
    for (int q = 0; q < 2; ++q) {
        int i = t + q * 256;
        bs[i] = h[i] ? atomicAdd(&cur[i], h[i]) : 0;
        cl[i] = 0;
    }
    __syncthreads();
    for (int e = beg + t; e < end; e += 256) {
        int d = dst[e];
        int bk = d >> BSH;
        int r = atomicAdd(&cl[bk], 1);
        int low = d & ((1 << BSH) - 1);
        ebuf[bs[bk] + r] = make_int2(src[e] | (low << 20), __float_as_int(w[e]));
    }
}

// ---------------- pass B: in-LDS counting sort per bucket -> CSR + degrees ----------------
__global__ __launch_bounds__(256) void passB_kernel(const int* __restrict__ boff,
                                                    const int2* __restrict__ ebuf,
                                                    int* __restrict__ srcS, float* __restrict__ wS,
                                                    int* __restrict__ row_off,
                                                    float* __restrict__ dinv_w,
                                                    float* __restrict__ dinv_1, int N) {
    constexpr int BN = 1 << BSH;   // 128 nodes per bucket
    __shared__ int2 eb[BCAP];
    __shared__ int hist[BN];
    __shared__ int tmp[256];
    __shared__ int loc[BN];
    __shared__ int cur[BN];
    __shared__ float dws[BN];

    int b = blockIdx.x;
    int t = threadIdx.x;
    int base = boff[b];
    int sz = boff[b + 1] - base;

    if (t < BN) hist[t] = 0;
    __syncthreads();
    for (int i = t; i < sz; i += 256) {
        int2 e = ebuf[base + i];
        eb[i] = e;
        atomicAdd(&hist[((unsigned)e.x) >> 20], 1);
    }
    __syncthreads();
    // exclusive scan of hist[0..BN)
    tmp[t] = (t < BN) ? hist[t] : 0;
    __syncthreads();
    for (int off = 1; off < BN; off <<= 1) {
        int u = (t >= off && t < BN) ? tmp[t - off] : 0;
        __syncthreads();
        if (t < BN) tmp[t] += u;
        __syncthreads();
    }
    int node = (b << BSH) + t;
    if (t < BN) {
        loc[t] = tmp[t] - hist[t];
        cur[t] = 0;
        dws[t] = 0.0f;
        if (node < N) {
            row_off[node] = base + loc[t];
            dinv_1[node] = rsqrtf((float)hist[t] + 1.0f);
        }
    }
    __syncthreads();
    for (int i = t; i < sz; i += 256) {
        int key = eb[i].x;
        int bk = ((unsigned)key) >> 20;
        float wv = __int_as_float(eb[i].y);
        int r = atomicAdd(&cur[bk], 1);
        int slot = base + loc[bk] + r;
        srcS[slot] = key & 0xFFFFF;
        wS[slot] = wv;
        atomicAdd(&dws[bk], wv);
    }
    __syncthreads();
    if (t < BN && node < N) dinv_w[node] = rsqrtf(dws[t] + 1.0f);
}

// ---------------- coefficients per CSR row ----------------
__global__ void coef8_kernel(const int* __restrict__ row_off, const int* __restrict__ srcS,
                             const float* __restrict__ wS,
                             const float* __restrict__ dinv_w, const float* __restrict__ dinv_1,
                             float* __restrict__ coefwS, float* __restrict__ coef1S, int N) {
    int n = blockIdx.x * 16 + (threadIdx.x >> 4);   // 16 nodes/block, 16 lanes/node
    int l = threadIdx.x & 15;
    if (n >= N) return;
    int beg = row_off[n], end = row_off[n + 1];
    float dw = dinv_w[n], d1 = dinv_1[n];
    for (int j = beg + l; j < end; j += 16) {
        int s = srcS[j];
        coefwS[j] = dinv_w[s] * wS[j] * dw;
        coef1S[j] = dinv_1[s] * d1;
    }
}

// ---------------- LDS-tiled GEMM: H = X @ W (+bias)(+relu) ----------------
template<int K, int DOUT, bool BIAS, bool RELU_OUT>
__global__ __launch_bounds__(256) void tgemm_kernel(const float* __restrict__ X,
                                                    const float* __restrict__ W,
                                                    const float* __restrict__ b,
                                                    float* __restrict__ H, int N) {
    constexpr int BK = 16;
    __shared__ float Xs[BK][68];
    __shared__ float Ws[BK][68];

    const int t = threadIdx.x;
    const int tx = t & 15;
    const int ty = t >> 4;
    const int brow = blockIdx.x * 64;
    const int bcol = blockIdx.y * 64;

    const int row_l = t >> 2;
    const int kq    = t & 3;
    int srow = brow + row_l;
    if (srow > N - 1) srow = N - 1;

    float acc[4][4] = {};

    for (int kc = 0; kc < K; kc += BK) {
        float4 xv = *reinterpret_cast<const float4*>(&X[srow * K + kc + kq * 4]);
        Xs[kq * 4 + 0][row_l] = xv.x;
        Xs[kq * 4 + 1][row_l] = xv.y;
        Xs[kq * 4 + 2][row_l] = xv.z;
        Xs[kq * 4 + 3][row_l] = xv.w;
        float4 wv = *reinterpret_cast<const float4*>(&W[(kc + ty) * DOUT + bcol + tx * 4]);
        *reinterpret_cast<float4*>(&Ws[ty][tx * 4]) = wv;
        __syncthreads();

#pragma unroll
        for (int kk = 0; kk < BK; ++kk) {
            float4 a = *reinterpret_cast<const float4*>(&Xs[kk][ty * 4]);
            float4 wr = *reinterpret_cast<const float4*>(&Ws[kk][tx * 4]);
            acc[0][0] += a.x * wr.x; acc[0][1] += a.x * wr.y; acc[0][2] += a.x * wr.z; acc[0][3] += a.x * wr.w;
            acc[1][0] += a.y * wr.x; acc[1][1] += a.y * wr.y; acc[1][2] += a.y * wr.z; acc[1][3] += a.y * wr.w;
            acc[2][0] += a.z * wr.x; acc[2][1] += a.z * wr.y; acc[2][2] += a.z * wr.z; acc[2][3] += a.z * wr.w;
            acc[3][0] += a.w * wr.x; acc[3][1] += a.w * wr.y; acc[3][2] += a.w * wr.z; acc[3][3] += a.w * wr.w;
        }
        __syncthreads();
    }

    float4 bv = make_float4(0.f, 0.f, 0.f, 0.f);
    if constexpr (BIAS) bv = *reinterpret_cast<const float4*>(&b[bcol + tx * 4]);
#pragma unroll
    for (int r = 0; r < 4; ++r) {
        int row = brow + ty * 4 + r;
        if (row < N) {
            float4 o = make_float4(acc[r][0] + bv.x, acc[r][1] + bv.y,
                                   acc[r][2] + bv.z, acc[r][3] + bv.w);
            if constexpr (RELU_OUT) {
                o.x = fmaxf(o.x, 0.f); o.y = fmaxf(o.y, 0.f);
                o.z = fmaxf(o.z, 0.f); o.w = fmaxf(o.w, 0.f);
            }
            *reinterpret_cast<float4*>(&H[row * DOUT + bcol + tx * 4]) = o;
        }
    }
}

// ---------------- simple register GEMM (small layers 2/3) ----------------
template<int K, int DOUT, bool BIAS, bool RELU_OUT>
__global__ void gemm_kernel(const float* __restrict__ X, const float* __restrict__ W,
                            const float* __restrict__ b, float* __restrict__ H, int N) {
    constexpr int CG = DOUT / 4;
    constexpr int RPB = (256 / CG) * 4;
    int tx = threadIdx.x % CG;
    int ty = threadIdx.x / CG;
    int row0 = blockIdx.x * RPB + ty * 4;
    int col0 = tx * 4;

    float acc[4][4] = {};
    for (int k = 0; k < K; k += 4) {
        float4 w0 = *reinterpret_cast<const float4*>(&W[(k + 0) * DOUT + col0]);
        float4 w1 = *reinterpret_cast<const float4*>(&W[(k + 1) * DOUT + col0]);
        float4 w2 = *reinterpret_cast<const float4*>(&W[(k + 2) * DOUT + col0]);
        float4 w3 = *reinterpret_cast<const float4*>(&W[(k + 3) * DOUT + col0]);
#pragma unroll
        for (int r = 0; r < 4; ++r) {
            int row = row0 + r;
            if (row < N) {
                float4 x4 = *reinterpret_cast<const float4*>(&X[row * K + k]);
                acc[r][0] += x4.x * w0.x + x4.y * w1.x + x4.z * w2.x + x4.w * w3.x;
                acc[r][1] += x4.x * w0.y + x4.y * w1.y + x4.z * w2.y + x4.w * w3.y;
                acc[r][2] += x4.x * w0.z + x4.y * w1.z + x4.z * w2.z + x4.w * w3.z;
                acc[r][3] += x4.x * w0.w + x4.y * w1.w + x4.z * w2.w + x4.w * w3.w;
            }
        }
    }
    float4 bv = make_float4(0.f, 0.f, 0.f, 0.f);
    if constexpr (BIAS) bv = *reinterpret_cast<const float4*>(&b[col0]);
#pragma unroll
    for (int r = 0; r < 4; ++r) {
        int row = row0 + r;
        if (row < N) {
            float4 o = make_float4(acc[r][0] + bv.x, acc[r][1] + bv.y,
                                   acc[r][2] + bv.z, acc[r][3] + bv.w);
            if constexpr (RELU_OUT) {
                o.x = fmaxf(o.x, 0.f); o.y = fmaxf(o.y, 0.f);
                o.z = fmaxf(o.z, 0.f); o.w = fmaxf(o.w, 0.f);
            }
            *reinterpret_cast<float4*>(&H[row * DOUT + col0]) = o;
        }
    }
}

// ---------------- pull aggregation (zero atomics, 8-wide unrolled gathers) ----------------
template<bool BIAS, bool RELU>
__global__ void pull64_kernel(const int* __restrict__ row_off, const int* __restrict__ srcS,
                              const float* __restrict__ coefS, const float* __restrict__ H,
                              const float* __restrict__ dinv, const float* __restrict__ b,
                              float* __restrict__ out, int N) {
    int node = blockIdx.x * 4 + (threadIdx.x >> 6);
    int f = threadIdx.x & 63;
    if (node >= N) return;
    int beg = row_off[node], end = row_off[node + 1];
    float a0 = 0.f, a1 = 0.f, a2 = 0.f, a3 = 0.f, a4 = 0.f, a5 = 0.f, a6 = 0.f, a7 = 0.f;
    int j = beg;
    int end8 = beg + ((end - beg) & ~7);
    for (; j < end8; j += 8) {
        int s0 = srcS[j+0], s1 = srcS[j+1], s2 = srcS[j+2], s3 = srcS[j+3];
        int s4 = srcS[j+4], s5 = srcS[j+5], s6 = srcS[j+6], s7 = srcS[j+7];
        float c0 = coefS[j+0], c1 = coefS[j+1], c2 = coefS[j+2], c3 = coefS[j+3];
        float c4 = coefS[j+4], c5 = coefS[j+5], c6 = coefS[j+6], c7 = coefS[j+7];
        float h0 = H[s0 * 64 + f], h1 = H[s1 * 64 + f], h2 = H[s2 * 64 + f], h3 = H[s3 * 64 + f];
        float h4 = H[s4 * 64 + f], h5 = H[s5 * 64 + f], h6 = H[s6 * 64 + f], h7 = H[s7 * 64 + f];
        a0 += h0 * c0; a1 += h1 * c1; a2 += h2 * c2; a3 += h3 * c3;
        a4 += h4 * c4; a5 += h5 * c5; a6 += h6 * c6; a7 += h7 * c7;
    }
    int end4 = j + ((end - j) & ~3);
    for (; j < end4; j += 4) {
        int s0 = srcS[j+0], s1 = srcS[j+1], s2 = srcS[j+2], s3 = srcS[j+3];
        float c0 = coefS[j+0], c1 = coefS[j+1], c2 = coefS[j+2], c3 = coefS[j+3];
        a0 += H[s0 * 64 + f] * c0; a1 += H[s1 * 64 + f] * c1;
        a2 += H[s2 * 64 + f] * c2; a3 += H[s3 * 64 + f] * c3;
    }
    for (; j < end; ++j) a0 += H[srcS[j] * 64 + f] * coefS[j];
    float acc = ((a0 + a1) + (a2 + a3)) + ((a4 + a5) + (a6 + a7));
    float di = dinv[node];
    float v = acc + H[node * 64 + f] * di * di;
    if constexpr (BIAS) v += b[f];
    if constexpr (RELU) v = fmaxf(v, 0.0f);
    out[node * 64 + f] = v;
}

template<bool BIAS, bool RELU>
__global__ void pull32_kernel(const int* __restrict__ row_off, const int* __restrict__ srcS,
                              const float* __restrict__ coefS, const float* __restrict__ H,
                              const float* __restrict__ dinv, const float* __restrict__ b,
                              float* __restrict__ out, float* __restrict__ out2, int N) {
    int node = blockIdx.x * 8 + (threadIdx.x >> 5);
    int f = threadIdx.x & 31;
    if (node >= N) return;
    int beg = row_off[node], end = row_off[node + 1];
    float a0 = 0.f, a1 = 0.f, a2 = 0.f, a3 = 0.f, a4 = 0.f, a5 = 0.f, a6 = 0.f, a7 = 0.f;
    int j = beg;
    int end8 = beg + ((end - beg) & ~7);
    for (; j < end8; j += 8) {
        int s0 = srcS[j+0], s1 = srcS[j+1], s2 = srcS[j+2], s3 = srcS[j+3];
        int s4 = srcS[j+4], s5 = srcS[j+5], s6 = srcS[j+6], s7 = srcS[j+7];
        float c0 = coefS[j+0], c1 = coefS[j+1], c2 = coefS[j+2], c3 = coefS[j+3];
        float c4 = coefS[j+4], c5 = coefS[j+5], c6 = coefS[j+6], c7 = coefS[j+7];
        float h0 = H[s0 * 32 + f], h1 = H[s1 * 32 + f], h2 = H[s2 * 32 + f], h3 = H[s3 * 32 + f];
        float h4 = H[s4 * 32 + f], h5 = H[s5 * 32 + f], h6 = H[s6 * 32 + f], h7 = H[s7 * 32 + f];
        a0 += h0 * c0; a1 += h1 * c1; a2 += h2 * c2; a3 += h3 * c3;
        a4 += h4 * c4; a5 += h5 * c5; a6 += h6 * c6; a7 += h7 * c7;
    }
    int end4 = j + ((end - j) & ~3);
    for (; j < end4; j += 4) {
        int s0 = srcS[j+0], s1 = srcS[j+1], s2 = srcS[j+2], s3 = srcS[j+3];
        float c0 = coefS[j+0], c1 = coefS[j+1], c2 = coefS[j+2], c3 = coefS[j+3];
        a0 += H[s0 * 32 + f] * c0; a1 += H[s1 * 32 + f] * c1;
        a2 += H[s2 * 32 + f] * c2; a3 += H[s3 * 32 + f] * c3;
    }
    for (; j < end; ++j) a0 += H[srcS[j] * 32 + f] * coefS[j];
    float acc = ((a0 + a1) + (a2 + a3)) + ((a4 + a5) + (a6 + a7));
    float di = dinv[node];
    float v = acc + H[node * 32 + f] * di * di;
    if constexpr (BIAS) v += b[f];
    if constexpr (RELU) v = fmaxf(v, 0.0f);
    out[node * 32 + f] = v;
    if (out2) out2[node * 32 + f] = v;
}

// ---------------- launch ----------------

extern "C" void kernel_launch(void* const* d_in, const int* in_sizes, int n_in,
                              void* d_out, int out_size, void* d_ws, size_t ws_size,
                              hipStream_t stream) {
    const float* x  = (const float*)d_in[0];
    const int*   ei = (const int*)d_in[1];
    const float* w  = (const float*)d_in[2];
    const float* W1 = (const float*)d_in[3];
    const float* b1 = (const float*)d_in[4];
    const float* W2 = (const float*)d_in[5];
    const float* b2 = (const float*)d_in[6];
    const float* W3 = (const float*)d_in[7];
    const float* b3 = (const float*)d_in[8];
    const float* W4 = (const float*)d_in[9];
    const float* b4 = (const float*)d_in[10];

    const int* src = ei;            // edge_index[0]
    const int* dst = ei + EE;       // edge_index[1]

    const int N = NN, E = EE;

    // workspace layout (4-byte words), total ~77.4 MB
    float* ws     = (float*)d_ws;
    float* dinv_w = ws;                       // NP
    float* dinv_1 = ws + 50176;               // NP
    int*   row_off= (int*)(ws + 100352);      // N+1 (pad NP)
    int*   bcnt   = (int*)(ws + 150528);      // 512
    int*   boff   = (int*)(ws + 151040);      // 513 (pad 768)
    int*   cur    = (int*)(ws + 151808);      // 512
    int2*  ebuf   = (int2*)(ws + 152320);     // E int2 (2E words)
    int*   srcS   = (int*)(ws + 1752320);     // E
    float* wS     = ws + 2552320;             // E
    float* coefwS = ws + 3352320;             // E
    float* coef1S = ws + 4152320;             // E
    float* g1     = ws + 4952320;             // N*64 (aliased by dbuf later)
    float* h1     = ws + 8152320;             // N*64
    float* g2     = ws + 11352320;            // N*32
    float* zws    = ws + 12952320;            // N*32
    float* p3     = ws + 14552320;            // N*32
    float* p4     = ws + 16152320;            // N*64 (end 19,352,320 words)
    float* dbuf   = g1;                       // g1 dead after L1 pull

    float* recon = (float*)d_out;             // N*256
    float* zout  = (float*)d_out + NN * 256;  // N*32

    // ---- CSR build + normalization (two-level bucket sort) ----
    hipMemsetAsync(bcnt, 0, 512 * sizeof(int), stream);
    histb_kernel<<<NBLKA, 256, 0, stream>>>(dst, bcnt, E);
    bscan_kernel<<<1, 512, 0, stream>>>(bcnt, boff, cur, row_off, E, N);
    passA_kernel<<<NBLKA, 256, 0, stream>>>(src, dst, w, cur, ebuf, E);
    passB_kernel<<<NBUK, 256, 0, stream>>>(boff, ebuf, srcS, wS, row_off, dinv_w, dinv_1, N);
    coef8_kernel<<<(N + 15) / 16, 256, 0, stream>>>(row_off, srcS, wS, dinv_w, dinv_1,
                                                    coefwS, coef1S, N);

    // ---- layer 1: h1 = relu(prop_w(x@W1) + b1) ----
    tgemm_kernel<256, 64, false, false><<<dim3((N + 63) / 64, 1), 256, 0, stream>>>(x, W1, nullptr, g1, N);
    pull64_kernel<true, true><<<(N + 3) / 4, 256, 0, stream>>>(row_off, srcS, coefwS, g1, dinv_w, b1, h1, N);

    // ---- layer 2: z = relu(prop_w(h1@W2) + b2) -> zws (+ copy to zout) ----
    gemm_kernel<64, 32, false, false><<<(N + 127) / 128, 256, 0, stream>>>(h1, W2, nullptr, g2, N);
    pull32_kernel<true, true><<<(N + 7) / 8, 256, 0, stream>>>(row_off, srcS, coefwS, g2, dinv_w, b2, zws, zout, N);

    // ---- layer 3: d = relu(prop_w(z) @ W3 + b3)   (propagate in 32-dim space) ----
    pull32_kernel<false, false><<<(N + 7) / 8, 256, 0, stream>>>(row_off, srcS, coefwS, zws, dinv_w, nullptr, p3, nullptr, N);
    gemm_kernel<32, 64, true, true><<<(N + 63) / 64, 256, 0, stream>>>(p3, W3, b3, dbuf, N);

    // ---- layer 4: recon = prop_1(d) @ W4 + b4     (propagate in 64-dim space) ----
    pull64_kernel<false, false><<<(N + 3) / 4, 256, 0, stream>>>(row_off, srcS, coef1S, dbuf, dinv_1, nullptr, p4, N);
    tgemm_kernel<64, 256, true, false><<<dim3((N + 63) / 64, 4), 256, 0, stream>>>(p4, W4, b4, recon, N);

    (void)in_sizes; (void)n_in; (void)out_size; (void)ws_size;
}